// Round 1
// baseline (2415.770 us; speedup 1.0000x reference)
//
#include <hip/hip_runtime.h>
#include <math.h>

#define N_USERS 50000
#define N_ITEMS 30000
#define N_ENT   100000
#define NE      500000      // KG edges E
#define NEI     1000000     // interaction edges EI
#define D       64
#define GAMMA   0.2f

__device__ __forceinline__ float wave_sum(float v) {
    #pragma unroll
    for (int off = 32; off > 0; off >>= 1) v += __shfl_xor(v, off, 64);
    return v;
}

__device__ __forceinline__ void atomicMaxF(float* addr, float v) {
    if (v >= 0.0f) atomicMax((int*)addr, __float_as_int(v));
    else           atomicMin((unsigned int*)addr, __float_as_uint(v));
}

__device__ __forceinline__ float sigmoidf(float x) { return 1.0f / (1.0f + expf(-x)); }

__device__ __forceinline__ float n2n(float y) {
    if (isnan(y)) return 0.0f;
    if (isinf(y)) return y > 0.0f ? 1e4f : 1e-4f;
    return y;
}

// ---------------- generic ----------------
__global__ void k_fill(float* p, float v, int n) {
    int i = blockIdx.x * blockDim.x + threadIdx.x;
    if (i < n) p[i] = v;
}

// ---------------- Stage A: attention preference miner ----------------
// Uq = user_embed @ Wq   (wave per row)
__global__ void k_proj_user(const float* __restrict__ U, const float* __restrict__ Wq,
                            float* __restrict__ Uq, int n) {
    int gw = (blockIdx.x * blockDim.x + threadIdx.x) >> 6;
    int lane = threadIdx.x & 63;
    if (gw >= n) return;
    const float* row = U + (size_t)gw * D;
    float acc = 0.f;
    #pragma unroll
    for (int k = 0; k < D; k++) acc += row[k] * Wq[k * D + lane];
    Uq[(size_t)gw * D + lane] = acc;
}

// Ik = item@Wk, Iv = item@Wv (shared row loads)
__global__ void k_proj_item(const float* __restrict__ I, const float* __restrict__ Wk,
                            const float* __restrict__ Wv, float* __restrict__ Ik,
                            float* __restrict__ Iv, int n) {
    int gw = (blockIdx.x * blockDim.x + threadIdx.x) >> 6;
    int lane = threadIdx.x & 63;
    if (gw >= n) return;
    const float* row = I + (size_t)gw * D;
    float ak = 0.f, av = 0.f;
    #pragma unroll
    for (int k = 0; k < D; k++) {
        float x = row[k];
        ak += x * Wk[k * D + lane];
        av += x * Wv[k * D + lane];
    }
    Ik[(size_t)gw * D + lane] = ak;
    Iv[(size_t)gw * D + lane] = av;
}

// scores[e] = dot(Uq[u],Ik[i])/8 * w[e];  segment max into m[u]
__global__ void k_scores(const int* __restrict__ ie, const float* __restrict__ w,
                         const float* __restrict__ Uq, const float* __restrict__ Ik,
                         float* __restrict__ scores, float* __restrict__ m, int nE) {
    int gw = (blockIdx.x * blockDim.x + threadIdx.x) >> 6;
    int lane = threadIdx.x & 63;
    if (gw >= nE) return;
    int u = ie[gw], it = ie[nE + gw];
    float prod = Uq[(size_t)u * D + lane] * Ik[(size_t)it * D + lane];
    prod = wave_sum(prod);
    if (lane == 0) {
        float s = prod * 0.125f * w[gw];
        scores[gw] = s;
        atomicMaxF(&m[u], s);
    }
}

// ex = exp(s - m[u]); den[u]+=ex; cnt[u]+=1; scores <- ex
__global__ void k_exp(const int* __restrict__ ie, float* __restrict__ scores,
                      const float* __restrict__ m, float* __restrict__ den,
                      float* __restrict__ cnt, int nE) {
    int e = blockIdx.x * blockDim.x + threadIdx.x;
    if (e >= nE) return;
    int u = ie[e];
    float ex = expf(scores[e] - m[u]);
    scores[e] = ex;
    atomicAdd(&den[u], ex);
    atomicAdd(&cnt[u], 1.0f);
}

// p[d] = sum_e (ex/den[u]/max(cnt,1)) * Iv[i][d]
__global__ void k_pvec(const int* __restrict__ ie, const float* __restrict__ ex,
                       const float* __restrict__ den, const float* __restrict__ cnt,
                       const float* __restrict__ Iv, float* __restrict__ p, int nE) {
    int lane = threadIdx.x & 63;
    int gw = blockIdx.x * (blockDim.x >> 6) + (threadIdx.x >> 6);
    int nw = gridDim.x * (blockDim.x >> 6);
    float acc = 0.f;
    for (int e = gw; e < nE; e += nw) {
        int u = ie[e], it = ie[nE + e];
        float coef = ex[e] / den[u] / fmaxf(cnt[u], 1.0f);
        acc += coef * Iv[(size_t)it * D + lane];
    }
    __shared__ float red[256];
    red[threadIdx.x] = acc;
    __syncthreads();
    if (threadIdx.x < 64) {
        float s = red[threadIdx.x] + red[threadIdx.x + 64] + red[threadIdx.x + 128] + red[threadIdx.x + 192];
        atomicAdd(&p[threadIdx.x], s);
    }
}

// v2[j] = sum_k rtW2[j][k]*p[k];  cb = dot(rt_b2, p)
__global__ void k_v2(const float* __restrict__ rtW2, const float* __restrict__ rt_b2,
                     const float* __restrict__ p, float* __restrict__ v2, float* __restrict__ cb) {
    int j = threadIdx.x;  // 64 threads
    float acc = 0.f;
    #pragma unroll
    for (int k = 0; k < D; k++) acc += rtW2[j * D + k] * p[k];
    v2[j] = acc;
    float c = rt_b2[j] * p[j];
    c = wave_sum(c);
    if (j == 0) cb[0] = c;
}

// ---------------- Stage B: fact-semantic + router -> omega ----------------
// Per-entity tables: EH = [er|ei]@fpW1[0:64], ET = [er|ei]@fpW1[128:192], PHI = [er|ei]@rtW1
__global__ void k_ent_tables(const float* __restrict__ er, const float* __restrict__ ei,
                             const float* __restrict__ fpW1, const float* __restrict__ rtW1,
                             float* __restrict__ EH, float* __restrict__ ET,
                             float* __restrict__ PHI, int n) {
    int gw = (blockIdx.x * blockDim.x + threadIdx.x) >> 6;
    int lane = threadIdx.x & 63;
    int u0 = gw * 4;
    if (u0 >= n) return;
    float aEH[4] = {0, 0, 0, 0}, aET[4] = {0, 0, 0, 0}, aPH[4] = {0, 0, 0, 0};
    for (int k = 0; k < 32; k++) {
        float w1a = fpW1[k * D + lane];
        float w1b = fpW1[(32 + k) * D + lane];
        float w1e = fpW1[(128 + k) * D + lane];
        float w1f = fpW1[(160 + k) * D + lane];
        float ra  = rtW1[k * D + lane];
        float rb  = rtW1[(32 + k) * D + lane];
        #pragma unroll
        for (int q = 0; q < 4; q++) {
            int u = u0 + q;
            float sr = er[(size_t)u * 32 + k];
            float si = ei[(size_t)u * 32 + k];
            aEH[q] += sr * w1a + si * w1b;
            aET[q] += sr * w1e + si * w1f;
            aPH[q] += sr * ra  + si * rb;
        }
    }
    #pragma unroll
    for (int q = 0; q < 4; q++) {
        int u = u0 + q;
        if (u < n) {
            EH[(size_t)u * D + lane]  = aEH[q];
            ET[(size_t)u * D + lane]  = aET[q];
            PHI[(size_t)u * D + lane] = aPH[q];
        }
    }
}

// relation tables: RR1 = [rr|ri]@fpW1[64:128], PSI = [rr|ri]@rtW1
__global__ void k_rel_tables(const float* __restrict__ rr, const float* __restrict__ ri,
                             const float* __restrict__ fpW1, const float* __restrict__ rtW1,
                             float* __restrict__ RR1, float* __restrict__ PSI) {
    int lane = threadIdx.x;  // 64
    for (int r = 0; r < 10; r++) {
        float a = 0.f, b = 0.f;
        for (int k = 0; k < 32; k++) {
            float sr = rr[r * 32 + k], si = ri[r * 32 + k];
            a += sr * fpW1[(64 + k) * D + lane] + si * fpW1[(96 + k) * D + lane];
            b += sr * rtW1[k * D + lane] + si * rtW1[(32 + k) * D + lane];
        }
        RR1[r * D + lane] = a;
        PSI[r * D + lane] = b;
    }
}

__global__ void k_omega(const int* __restrict__ eidx, const int* __restrict__ etype,
                        const float* __restrict__ EH, const float* __restrict__ ET,
                        const float* __restrict__ PHI, const float* __restrict__ RR1,
                        const float* __restrict__ PSI, const float* __restrict__ fp_b1,
                        const float* __restrict__ fpW2, const float* __restrict__ fp_b2,
                        const float* __restrict__ rt_b1, const float* __restrict__ v2,
                        const float* __restrict__ cb, float* __restrict__ omega, int nE) {
    int gw = (blockIdx.x * blockDim.x + threadIdx.x) >> 6;
    int lane = threadIdx.x & 63;
    if (gw >= nE) return;
    int h = eidx[gw], t = eidx[nE + gw], r = etype[gw] - 1;
    float z1 = sigmoidf(EH[(size_t)h * D + lane] + RR1[r * D + lane] +
                        ET[(size_t)t * D + lane] + fp_b1[lane]);
    float a0 = z1 * fpW2[lane * 3 + 0];
    float a1 = z1 * fpW2[lane * 3 + 1];
    float a2 = z1 * fpW2[lane * 3 + 2];
    a0 = wave_sum(a0); a1 = wave_sum(a1); a2 = wave_sum(a2);
    a0 += fp_b2[0]; a1 += fp_b2[1]; a2 += fp_b2[2];
    float mx = fmaxf(a0, fmaxf(a1, a2));
    float e0 = expf(a0 - mx), e1 = expf(a1 - mx), e2 = expf(a2 - mx);
    float inv = 1.0f / (e0 + e1 + e2);
    float w0 = e0 * inv, w1 = e1 * inv, w2 = e2 * inv;
    float t2 = w0 * PHI[(size_t)h * D + lane] + w1 * PSI[r * D + lane] +
               w2 * PHI[(size_t)t * D + lane] + rt_b1[lane];
    float s = sigmoidf(t2) * v2[lane];
    s = wave_sum(s);
    if (lane == 0) omega[gw] = (s + cb[0]) * 0.125f;
}

// ---------------- Stage C: graph conv ----------------
__global__ void k_sego(const int* __restrict__ eidx, const float* __restrict__ omega,
                       float* __restrict__ seg_o, float* __restrict__ cnt_h, int nE) {
    int e = blockIdx.x * blockDim.x + threadIdx.x;
    if (e >= nE) return;
    int h = eidx[e];
    atomicAdd(&seg_o[h], omega[e]);
    atomicAdd(&cnt_h[h], 1.0f);
}

__global__ void k_alpha(const int* __restrict__ eidx, const float* __restrict__ omega,
                        const float* __restrict__ seg_o, float* __restrict__ alpha_g,
                        float* __restrict__ eta, float* __restrict__ seg_e, int nE) {
    int e = blockIdx.x * blockDim.x + threadIdx.x;
    if (e >= nE) return;
    int h = eidx[e];
    float a = omega[e] / (seg_o[h] + 1e-8f);
    alpha_g[e] = a;
    float et = a > GAMMA ? a : 0.0f;
    eta[e] = et;
    atomicAdd(&seg_e[h], et);
}

__global__ void k_etanorm(const int* __restrict__ eidx, float* __restrict__ eta,
                          const float* __restrict__ seg_e, int nE) {
    int e = blockIdx.x * blockDim.x + threadIdx.x;
    if (e >= nE) return;
    int h = eidx[e];
    eta[e] = eta[e] / (seg_e[h] + 1e-8f);
}

__global__ void k_eagg(const int* __restrict__ eidx, const int* __restrict__ etype,
                       const float* __restrict__ rho, const float* __restrict__ e_emb,
                       const float* __restrict__ rel_emb, float* __restrict__ e_agg, int nE) {
    int gw = (blockIdx.x * blockDim.x + threadIdx.x) >> 6;
    int lane = threadIdx.x & 63;
    if (gw >= nE) return;
    int h = eidx[gw], t = eidx[nE + gw], r = etype[gw] - 1;
    float v = rho[gw] * e_emb[(size_t)t * D + lane] * rel_emb[r * D + lane];
    atomicAdd(&e_agg[(size_t)h * D + lane], v);
}

__global__ void k_uagg(const int* __restrict__ ie, const float* __restrict__ w,
                       const float* __restrict__ e_emb, float* __restrict__ u_agg, int nE) {
    int gw = (blockIdx.x * blockDim.x + threadIdx.x) >> 6;
    int lane = threadIdx.x & 63;
    if (gw >= nE) return;
    int u = ie[gw], it = ie[nE + gw];
    float v = w[gw] * e_emb[(size_t)it * D + lane];
    atomicAdd(&u_agg[(size_t)u * D + lane], v);
}

__global__ void k_enorm(const float* __restrict__ e_agg, const float* __restrict__ cnt_h,
                        float* __restrict__ e_emb, float* __restrict__ out, int n) {
    int gw = (blockIdx.x * blockDim.x + threadIdx.x) >> 6;
    int lane = threadIdx.x & 63;
    if (gw >= n) return;
    float x = e_agg[(size_t)gw * D + lane] / fmaxf(cnt_h[gw], 1.0f);
    float ss = wave_sum(x * x);
    float nrm = sqrtf(ss);
    float y = n2n(x / fmaxf(nrm, 1e-8f));
    e_emb[(size_t)gw * D + lane] = y;
    out[(size_t)gw * D + lane] += y;
}

__global__ void k_unorm(const float* __restrict__ u_agg, float* __restrict__ out, int n) {
    int gw = (blockIdx.x * blockDim.x + threadIdx.x) >> 6;
    int lane = threadIdx.x & 63;
    if (gw >= n) return;
    float x = u_agg[(size_t)gw * D + lane];
    float ss = wave_sum(x * x);
    float nrm = sqrtf(ss);
    float y = n2n(x / fmaxf(nrm, 1e-8f));
    out[(size_t)gw * D + lane] += y;
}

extern "C" void kernel_launch(void* const* d_in, const int* in_sizes, int n_in,
                              void* d_out, int out_size, void* d_ws, size_t ws_size,
                              hipStream_t stream) {
    const float* user_embed = (const float*)d_in[0];
    const float* item_embed = (const float*)d_in[1];
    const float* Wq = (const float*)d_in[2];
    const float* Wk = (const float*)d_in[3];
    const float* Wv = (const float*)d_in[4];
    const float* ent_real = (const float*)d_in[5];
    const float* ent_imag = (const float*)d_in[6];
    const float* rel_real = (const float*)d_in[7];
    const float* rel_imag = (const float*)d_in[8];
    const float* fp_W1 = (const float*)d_in[9];
    const float* fp_b1 = (const float*)d_in[10];
    const float* fp_W2 = (const float*)d_in[11];
    const float* fp_b2 = (const float*)d_in[12];
    const float* rt_W1 = (const float*)d_in[13];
    const float* rt_b1 = (const float*)d_in[14];
    const float* rt_W2 = (const float*)d_in[15];
    const float* rt_b2 = (const float*)d_in[16];
    const float* relation_emb = (const float*)d_in[17];
    const float* user_emb = (const float*)d_in[18];
    const float* entity_emb = (const float*)d_in[19];
    const float* inter_edge_w = (const float*)d_in[20];
    const int* edge_index = (const int*)d_in[21];
    const int* edge_type = (const int*)d_in[22];
    const int* inter_edge = (const int*)d_in[23];
    float* out = (float*)d_out;

    float* W = (float*)d_ws;
    size_t off = 0;
    auto alloc = [&](size_t n) { float* r = W + off; off += n; return r; };
    float* omega   = alloc(NE);
    float* seg_o   = alloc(N_ENT);
    float* seg_e   = alloc(N_ENT);
    float* cnt_h   = alloc(N_ENT);
    float* alpha_g = alloc(NE);
    float* eta     = alloc(NE);
    float* p       = alloc(64);
    float* v2      = alloc(64);
    float* cb      = alloc(64);
    float* U = W + off;  // union region, reused per phase
    // phase A layout
    float* Uq = U;
    float* Ik = Uq + (size_t)N_USERS * D;
    float* Iv = Ik + (size_t)N_ITEMS * D;
    float* scores = Iv + (size_t)N_ITEMS * D;
    float* m = scores + NEI;
    float* den = m + N_USERS;
    float* cnt_u = den + N_USERS;
    // phase B layout (overwrites phase A)
    float* EH = U;
    float* ET = EH + (size_t)N_ENT * D;
    float* PHI = ET + (size_t)N_ENT * D;
    float* RR1 = PHI + (size_t)N_ENT * D;
    float* PSI = RR1 + 10 * D;
    // phase C layout (overwrites phase B)
    float* e_emb = U;
    float* e_agg = e_emb + (size_t)N_ENT * D;
    float* u_agg = e_agg + (size_t)N_ENT * D;

    // ---- Phase A ----
    hipMemsetAsync(den, 0, N_USERS * 4, stream);
    hipMemsetAsync(cnt_u, 0, N_USERS * 4, stream);
    hipMemsetAsync(p, 0, 64 * 4, stream);
    k_fill<<<(N_USERS + 255) / 256, 256, 0, stream>>>(m, -INFINITY, N_USERS);
    k_proj_user<<<(N_USERS + 3) / 4, 256, 0, stream>>>(user_embed, Wq, Uq, N_USERS);
    k_proj_item<<<(N_ITEMS + 3) / 4, 256, 0, stream>>>(item_embed, Wk, Wv, Ik, Iv, N_ITEMS);
    k_scores<<<(NEI + 3) / 4, 256, 0, stream>>>(inter_edge, inter_edge_w, Uq, Ik, scores, m, NEI);
    k_exp<<<(NEI + 255) / 256, 256, 0, stream>>>(inter_edge, scores, m, den, cnt_u, NEI);
    k_pvec<<<512, 256, 0, stream>>>(inter_edge, scores, den, cnt_u, Iv, p, NEI);
    k_v2<<<1, 64, 0, stream>>>(rt_W2, rt_b2, p, v2, cb);

    // ---- Phase B ----
    k_ent_tables<<<(N_ENT / 4 + 3) / 4, 256, 0, stream>>>(ent_real, ent_imag, fp_W1, rt_W1,
                                                          EH, ET, PHI, N_ENT);
    k_rel_tables<<<1, 64, 0, stream>>>(rel_real, rel_imag, fp_W1, rt_W1, RR1, PSI);
    k_omega<<<(NE + 3) / 4, 256, 0, stream>>>(edge_index, edge_type, EH, ET, PHI, RR1, PSI,
                                              fp_b1, fp_W2, fp_b2, rt_b1, v2, cb, omega, NE);

    // ---- Graph prelims ----
    hipMemsetAsync(seg_o, 0, N_ENT * 4, stream);
    hipMemsetAsync(seg_e, 0, N_ENT * 4, stream);
    hipMemsetAsync(cnt_h, 0, N_ENT * 4, stream);
    k_sego<<<(NE + 255) / 256, 256, 0, stream>>>(edge_index, omega, seg_o, cnt_h, NE);
    k_alpha<<<(NE + 255) / 256, 256, 0, stream>>>(edge_index, omega, seg_o, alpha_g, eta, seg_e, NE);
    k_etanorm<<<(NE + 255) / 256, 256, 0, stream>>>(edge_index, eta, seg_e, NE);

    // ---- init residuals + e_emb ----
    hipMemcpyAsync(out, entity_emb, (size_t)N_ENT * D * 4, hipMemcpyDeviceToDevice, stream);
    hipMemcpyAsync(out + (size_t)N_ENT * D, user_emb, (size_t)N_USERS * D * 4,
                   hipMemcpyDeviceToDevice, stream);
    hipMemcpyAsync(e_emb, entity_emb, (size_t)N_ENT * D * 4, hipMemcpyDeviceToDevice, stream);

    // ---- hops ----
    for (int hop = 1; hop <= 3; hop++) {
        hipMemsetAsync(e_agg, 0, (size_t)N_ENT * D * 4, stream);
        hipMemsetAsync(u_agg, 0, (size_t)N_USERS * D * 4, stream);
        const float* rho = (hop < 3) ? alpha_g : eta;
        k_eagg<<<(NE + 3) / 4, 256, 0, stream>>>(edge_index, edge_type, rho, e_emb,
                                                 relation_emb, e_agg, NE);
        k_uagg<<<(NEI + 3) / 4, 256, 0, stream>>>(inter_edge, inter_edge_w, e_emb, u_agg, NEI);
        k_enorm<<<(N_ENT + 3) / 4, 256, 0, stream>>>(e_agg, cnt_h, e_emb, out, N_ENT);
        k_unorm<<<(N_USERS + 3) / 4, 256, 0, stream>>>(u_agg, out + (size_t)N_ENT * D, N_USERS);
    }
}

// Round 2
// 1807.436 us; speedup vs baseline: 1.3366x; 1.3366x over previous
//
#include <hip/hip_runtime.h>
#include <math.h>

#define N_USERS 50000
#define N_ITEMS 30000
#define N_ENT   100000
#define NE      500000      // KG edges E
#define NEI     1000000     // interaction edges EI
#define D       64
#define GAMMA   0.2f

__device__ __forceinline__ float wave_sum(float v) {
    #pragma unroll
    for (int off = 32; off > 0; off >>= 1) v += __shfl_xor(v, off, 64);
    return v;
}

__device__ __forceinline__ float sigmoidf(float x) { return 1.0f / (1.0f + expf(-x)); }

__device__ __forceinline__ float n2n(float y) {
    if (isnan(y)) return 0.0f;
    if (isinf(y)) return y > 0.0f ? 1e4f : 1e-4f;
    return y;
}

// ================= CSR build =================
__global__ void k_hist(const int* __restrict__ idx, int* __restrict__ cnt, int n) {
    int e = blockIdx.x * blockDim.x + threadIdx.x;
    if (e < n) atomicAdd(&cnt[idx[e]], 1);
}

// chunk = 1024 elems per block (256 thr x 4). off gets intra-chunk exclusive scan.
__global__ void k_scan1(const int* __restrict__ cnt, int* __restrict__ off,
                        int* __restrict__ bsum, int n) {
    __shared__ int sh[256];
    int t = threadIdx.x;
    int base = blockIdx.x * 1024 + t * 4;
    int v[4];
    #pragma unroll
    for (int j = 0; j < 4; j++) v[j] = (base + j < n) ? cnt[base + j] : 0;
    int tot = v[0] + v[1] + v[2] + v[3];
    sh[t] = tot;
    __syncthreads();
    for (int d = 1; d < 256; d <<= 1) {
        int x = (t >= d) ? sh[t - d] : 0;
        __syncthreads();
        sh[t] += x;
        __syncthreads();
    }
    int run = sh[t] - tot;
    #pragma unroll
    for (int j = 0; j < 4; j++) {
        if (base + j < n) off[base + j] = run;
        run += v[j];
    }
    if (t == 255) bsum[blockIdx.x] = sh[255];
}

// exclusive scan of nb (<=256) block sums; bsx[nb] = total
__global__ void k_scan2(const int* __restrict__ bsum, int* __restrict__ bsx, int nb) {
    __shared__ int sh[256];
    int t = threadIdx.x;
    int v = (t < nb) ? bsum[t] : 0;
    sh[t] = v;
    __syncthreads();
    for (int d = 1; d < 256; d <<= 1) {
        int x = (t >= d) ? sh[t - d] : 0;
        __syncthreads();
        sh[t] += x;
        __syncthreads();
    }
    if (t < nb) bsx[t] = sh[t] - v;
    if (t == 255) bsx[nb] = sh[255];
}

__global__ void k_scan3(int* __restrict__ off, int* __restrict__ cur,
                        const int* __restrict__ bsx, int n, int nb) {
    int i = blockIdx.x * blockDim.x + threadIdx.x;
    if (i > n) return;
    int val = (i == n) ? bsx[nb] : off[i] + bsx[i >> 10];
    off[i] = val;
    if (i < n) cur[i] = val;
}

__global__ void k_scatterU(const int* __restrict__ ie, const float* __restrict__ w,
                           int* __restrict__ cur, int* __restrict__ csr_it,
                           float* __restrict__ csr_w, int n) {
    int e = blockIdx.x * blockDim.x + threadIdx.x;
    if (e >= n) return;
    int u = ie[e], it = ie[n + e];
    int pos = atomicAdd(&cur[u], 1);
    csr_it[pos] = it;
    csr_w[pos] = w[e];
}

// KG scatter: stores packed (t | r<<20), alpha, normalized eta
__global__ void k_scatterH(const int* __restrict__ eidx, const int* __restrict__ etype,
                           const float* __restrict__ alpha_g, const float* __restrict__ seg_e,
                           int* __restrict__ cur, int* __restrict__ csr_tr,
                           float* __restrict__ csr_a, float* __restrict__ csr_et, int n) {
    int e = blockIdx.x * blockDim.x + threadIdx.x;
    if (e >= n) return;
    int h = eidx[e], t = eidx[n + e], r = etype[e] - 1;
    float a = alpha_g[e];
    float et = (a > GAMMA ? a : 0.0f) / (seg_e[h] + 1e-8f);
    int pos = atomicAdd(&cur[h], 1);
    csr_tr[pos] = t | (r << 20);
    csr_a[pos] = a;
    csr_et[pos] = et;
}

// ================= Stage A =================
__global__ void k_proj_user(const float* __restrict__ U, const float* __restrict__ Wq,
                            float* __restrict__ Uq, int n) {
    int gw = (blockIdx.x * blockDim.x + threadIdx.x) >> 6;
    int lane = threadIdx.x & 63;
    if (gw >= n) return;
    const float* row = U + (size_t)gw * D;
    float acc = 0.f;
    #pragma unroll
    for (int k = 0; k < D; k++) acc += row[k] * Wq[k * D + lane];
    Uq[(size_t)gw * D + lane] = acc;
}

__global__ void k_proj_item(const float* __restrict__ I, const float* __restrict__ Wk,
                            const float* __restrict__ Wv, float* __restrict__ Ik,
                            float* __restrict__ Iv, int n) {
    int gw = (blockIdx.x * blockDim.x + threadIdx.x) >> 6;
    int lane = threadIdx.x & 63;
    if (gw >= n) return;
    const float* row = I + (size_t)gw * D;
    float ak = 0.f, av = 0.f;
    #pragma unroll
    for (int k = 0; k < D; k++) {
        float x = row[k];
        ak += x * Wk[k * D + lane];
        av += x * Wv[k * D + lane];
    }
    Ik[(size_t)gw * D + lane] = ak;
    Iv[(size_t)gw * D + lane] = av;
}

// ex[e] = exp(score); den[u] += ex.  (max-shift dropped: scores are O(0.1),
// softmax is shift-invariant; no overflow possible at these magnitudes)
__global__ void k_scores_exp(const int* __restrict__ ie, const float* __restrict__ w,
                             const float* __restrict__ Uq, const float* __restrict__ Ik,
                             float* __restrict__ ex, float* __restrict__ den, int nE) {
    int gw = (blockIdx.x * blockDim.x + threadIdx.x) >> 6;
    int lane = threadIdx.x & 63;
    if (gw >= nE) return;
    int u = ie[gw], it = ie[nE + gw];
    float prod = Uq[(size_t)u * D + lane] * Ik[(size_t)it * D + lane];
    prod = wave_sum(prod);
    if (lane == 0) {
        float e = expf(prod * 0.125f * w[gw]);
        ex[gw] = e;
        atomicAdd(&den[u], e);
    }
}

// c[it] += ex/den[u]/max(deg_u,1)
__global__ void k_coef(const int* __restrict__ ie, const float* __restrict__ ex,
                       const float* __restrict__ den, const int* __restrict__ cntU,
                       float* __restrict__ c, int nE) {
    int e = blockIdx.x * blockDim.x + threadIdx.x;
    if (e >= nE) return;
    int u = ie[e], it = ie[nE + e];
    float coef = ex[e] / den[u] / fmaxf((float)cntU[u], 1.0f);
    atomicAdd(&c[it], coef);
}

// p[d] = sum_i c[i] * Iv[i][d]
__global__ void k_pdense(const float* __restrict__ c, const float* __restrict__ Iv,
                         float* __restrict__ p, int n) {
    int lane = threadIdx.x & 63;
    int gw = blockIdx.x * 4 + (threadIdx.x >> 6);
    int nw = gridDim.x * 4;
    float acc = 0.f;
    for (int i = gw; i < n; i += nw) acc += c[i] * Iv[(size_t)i * D + lane];
    __shared__ float red[256];
    red[threadIdx.x] = acc;
    __syncthreads();
    if (threadIdx.x < 64) {
        float s = red[threadIdx.x] + red[threadIdx.x + 64] + red[threadIdx.x + 128] + red[threadIdx.x + 192];
        atomicAdd(&p[threadIdx.x], s);
    }
}

__global__ void k_v2(const float* __restrict__ rtW2, const float* __restrict__ rt_b2,
                     const float* __restrict__ p, float* __restrict__ v2, float* __restrict__ cb) {
    int j = threadIdx.x;  // 64 threads
    float acc = 0.f;
    #pragma unroll
    for (int k = 0; k < D; k++) acc += rtW2[j * D + k] * p[k];
    v2[j] = acc;
    float c = rt_b2[j] * p[j];
    c = wave_sum(c);
    if (j == 0) cb[0] = c;
}

// ================= Stage B =================
// EH = [er|ei]@fpW1[0:64], ET = [er|ei]@fpW1[128:192]
__global__ void k_ent_ab(const float* __restrict__ er, const float* __restrict__ ei,
                         const float* __restrict__ fpW1, float* __restrict__ EH,
                         float* __restrict__ ET, int n) {
    int gw = (blockIdx.x * blockDim.x + threadIdx.x) >> 6;
    int lane = threadIdx.x & 63;
    int u0 = gw * 4;
    if (u0 >= n) return;
    float aEH[4] = {0, 0, 0, 0}, aET[4] = {0, 0, 0, 0};
    for (int k = 0; k < 32; k++) {
        float w1a = fpW1[k * D + lane];
        float w1b = fpW1[(32 + k) * D + lane];
        float w1e = fpW1[(128 + k) * D + lane];
        float w1f = fpW1[(160 + k) * D + lane];
        #pragma unroll
        for (int q = 0; q < 4; q++) {
            int u = u0 + q;
            float sr = er[(size_t)u * 32 + k];
            float si = ei[(size_t)u * 32 + k];
            aEH[q] += sr * w1a + si * w1b;
            aET[q] += sr * w1e + si * w1f;
        }
    }
    #pragma unroll
    for (int q = 0; q < 4; q++) {
        int u = u0 + q;
        if (u < n) {
            EH[(size_t)u * D + lane] = aEH[q];
            ET[(size_t)u * D + lane] = aET[q];
        }
    }
}

// PHI = [er|ei]@rtW1
__global__ void k_ent_phi(const float* __restrict__ er, const float* __restrict__ ei,
                          const float* __restrict__ rtW1, float* __restrict__ PHI, int n) {
    int gw = (blockIdx.x * blockDim.x + threadIdx.x) >> 6;
    int lane = threadIdx.x & 63;
    int u0 = gw * 4;
    if (u0 >= n) return;
    float aPH[4] = {0, 0, 0, 0};
    for (int k = 0; k < 32; k++) {
        float ra = rtW1[k * D + lane];
        float rb = rtW1[(32 + k) * D + lane];
        #pragma unroll
        for (int q = 0; q < 4; q++) {
            int u = u0 + q;
            aPH[q] += er[(size_t)u * 32 + k] * ra + ei[(size_t)u * 32 + k] * rb;
        }
    }
    #pragma unroll
    for (int q = 0; q < 4; q++) {
        int u = u0 + q;
        if (u < n) PHI[(size_t)u * D + lane] = aPH[q];
    }
}

__global__ void k_rel_tables(const float* __restrict__ rr, const float* __restrict__ ri,
                             const float* __restrict__ fpW1, const float* __restrict__ rtW1,
                             float* __restrict__ RR1, float* __restrict__ PSI) {
    int lane = threadIdx.x;  // 64
    for (int r = 0; r < 10; r++) {
        float a = 0.f, b = 0.f;
        for (int k = 0; k < 32; k++) {
            float sr = rr[r * 32 + k], si = ri[r * 32 + k];
            a += sr * fpW1[(64 + k) * D + lane] + si * fpW1[(96 + k) * D + lane];
            b += sr * rtW1[k * D + lane] + si * rtW1[(32 + k) * D + lane];
        }
        RR1[r * D + lane] = a;
        PSI[r * D + lane] = b;
    }
}

// pass 1: softmax gate weights per edge
__global__ void k_omega1(const int* __restrict__ eidx, const int* __restrict__ etype,
                         const float* __restrict__ EH, const float* __restrict__ ET,
                         const float* __restrict__ RR1, const float* __restrict__ fp_b1,
                         const float* __restrict__ fpW2, const float* __restrict__ fp_b2,
                         float* __restrict__ w0a, float* __restrict__ w1a,
                         float* __restrict__ w2a, int nE) {
    int gw = (blockIdx.x * blockDim.x + threadIdx.x) >> 6;
    int lane = threadIdx.x & 63;
    if (gw >= nE) return;
    int h = eidx[gw], t = eidx[nE + gw], r = etype[gw] - 1;
    float z1 = sigmoidf(EH[(size_t)h * D + lane] + RR1[r * D + lane] +
                        ET[(size_t)t * D + lane] + fp_b1[lane]);
    float a0 = wave_sum(z1 * fpW2[lane * 3 + 0]) + fp_b2[0];
    float a1 = wave_sum(z1 * fpW2[lane * 3 + 1]) + fp_b2[1];
    float a2 = wave_sum(z1 * fpW2[lane * 3 + 2]) + fp_b2[2];
    if (lane == 0) {
        float mx = fmaxf(a0, fmaxf(a1, a2));
        float e0 = expf(a0 - mx), e1 = expf(a1 - mx), e2 = expf(a2 - mx);
        float inv = 1.0f / (e0 + e1 + e2);
        w0a[gw] = e0 * inv;
        w1a[gw] = e1 * inv;
        w2a[gw] = e2 * inv;
    }
}

// pass 2: omega
__global__ void k_omega2(const int* __restrict__ eidx, const int* __restrict__ etype,
                         const float* __restrict__ PHI, const float* __restrict__ PSI,
                         const float* __restrict__ rt_b1, const float* __restrict__ v2,
                         const float* __restrict__ cb, const float* __restrict__ w0a,
                         const float* __restrict__ w1a, const float* __restrict__ w2a,
                         float* __restrict__ omega, int nE) {
    int gw = (blockIdx.x * blockDim.x + threadIdx.x) >> 6;
    int lane = threadIdx.x & 63;
    if (gw >= nE) return;
    int h = eidx[gw], t = eidx[nE + gw], r = etype[gw] - 1;
    float t2 = w0a[gw] * PHI[(size_t)h * D + lane] + w1a[gw] * PSI[r * D + lane] +
               w2a[gw] * PHI[(size_t)t * D + lane] + rt_b1[lane];
    float s = wave_sum(sigmoidf(t2) * v2[lane]);
    if (lane == 0) omega[gw] = (s + cb[0]) * 0.125f;
}

// ================= graph prelims =================
__global__ void k_sego(const int* __restrict__ eidx, const float* __restrict__ omega,
                       float* __restrict__ seg_o, int nE) {
    int e = blockIdx.x * blockDim.x + threadIdx.x;
    if (e >= nE) return;
    atomicAdd(&seg_o[eidx[e]], omega[e]);
}

__global__ void k_alpha(const int* __restrict__ eidx, const float* __restrict__ omega,
                        const float* __restrict__ seg_o, float* __restrict__ alpha_g,
                        float* __restrict__ seg_e, int nE) {
    int e = blockIdx.x * blockDim.x + threadIdx.x;
    if (e >= nE) return;
    int h = eidx[e];
    float a = omega[e] / (seg_o[h] + 1e-8f);
    alpha_g[e] = a;
    float et = a > GAMMA ? a : 0.0f;
    if (et != 0.0f) atomicAdd(&seg_e[h], et);
}

// ================= hops (CSR gather, fused normalize) =================
__global__ void k_hop_e(const int* __restrict__ off, const int* __restrict__ tr,
                        const float* __restrict__ aArr, const float* __restrict__ etArr,
                        const float* __restrict__ rel, const float* __restrict__ ecur,
                        float* __restrict__ enxt, float* __restrict__ out,
                        int useEta, int n) {
    int gw = (blockIdx.x * blockDim.x + threadIdx.x) >> 6;
    int lane = threadIdx.x & 63;
    if (gw >= n) return;
    int s = off[gw], epos = off[gw + 1];
    float acc = 0.f;
    for (int j = s; j < epos; j++) {
        int pk = tr[j];
        float rho = useEta ? etArr[j] : aArr[j];
        acc += rho * ecur[(size_t)(pk & 0xFFFFF) * D + lane] * rel[(pk >> 20) * D + lane];
    }
    float x = acc / fmaxf((float)(epos - s), 1.0f);
    float nrm = sqrtf(wave_sum(x * x));
    float y = n2n(x / fmaxf(nrm, 1e-8f));
    enxt[(size_t)gw * D + lane] = y;
    out[(size_t)gw * D + lane] += y;
}

__global__ void k_hop_u(const int* __restrict__ off, const int* __restrict__ itArr,
                        const float* __restrict__ wArr, const float* __restrict__ ecur,
                        float* __restrict__ out, int n) {
    int gw = (blockIdx.x * blockDim.x + threadIdx.x) >> 6;
    int lane = threadIdx.x & 63;
    if (gw >= n) return;
    int s = off[gw], epos = off[gw + 1];
    float acc = 0.f;
    for (int j = s; j < epos; j++)
        acc += wArr[j] * ecur[(size_t)itArr[j] * D + lane];
    float nrm = sqrtf(wave_sum(acc * acc));
    float y = n2n(acc / fmaxf(nrm, 1e-8f));
    out[(size_t)gw * D + lane] += y;
}

extern "C" void kernel_launch(void* const* d_in, const int* in_sizes, int n_in,
                              void* d_out, int out_size, void* d_ws, size_t ws_size,
                              hipStream_t stream) {
    const float* user_embed = (const float*)d_in[0];
    const float* item_embed = (const float*)d_in[1];
    const float* Wq = (const float*)d_in[2];
    const float* Wk = (const float*)d_in[3];
    const float* Wv = (const float*)d_in[4];
    const float* ent_real = (const float*)d_in[5];
    const float* ent_imag = (const float*)d_in[6];
    const float* rel_real = (const float*)d_in[7];
    const float* rel_imag = (const float*)d_in[8];
    const float* fp_W1 = (const float*)d_in[9];
    const float* fp_b1 = (const float*)d_in[10];
    const float* fp_W2 = (const float*)d_in[11];
    const float* fp_b2 = (const float*)d_in[12];
    const float* rt_W1 = (const float*)d_in[13];
    const float* rt_b1 = (const float*)d_in[14];
    const float* rt_W2 = (const float*)d_in[15];
    const float* rt_b2 = (const float*)d_in[16];
    const float* relation_emb = (const float*)d_in[17];
    const float* user_emb = (const float*)d_in[18];
    const float* entity_emb = (const float*)d_in[19];
    const float* inter_edge_w = (const float*)d_in[20];
    const int* edge_index = (const int*)d_in[21];
    const int* edge_type = (const int*)d_in[22];
    const int* inter_edge = (const int*)d_in[23];
    float* out = (float*)d_out;

    float* W = (float*)d_ws;
    size_t off = 0;
    auto alloc = [&](size_t n) { float* r = W + off; off += n; return r; };
    // ---- persistent (floats) ----
    float* omega   = alloc(NE);
    float* seg_o   = alloc(N_ENT);
    float* seg_e   = alloc(N_ENT);
    float* alpha_g = alloc(NE);
    float* w0a     = alloc(NE);
    float* w1a     = alloc(NE);
    float* w2a     = alloc(NE);
    float* den     = alloc(N_USERS);
    float* c       = alloc(N_ITEMS);
    float* p       = alloc(64);
    float* v2      = alloc(64);
    float* cb      = alloc(64);
    float* RR1     = alloc(10 * D);
    float* PSI     = alloc(10 * D);
    float* csr_a   = alloc(NE);
    float* csr_et  = alloc(NE);
    float* csr_w   = alloc(NEI);
    // ---- persistent (ints) ----
    int* IW = (int*)(W + off);
    size_t ioff = 0;
    auto ialloc = [&](size_t n) { int* r = IW + ioff; ioff += n; return r; };
    int* cntU   = ialloc(N_USERS);
    int* offU   = ialloc(N_USERS + 1);
    int* curU   = ialloc(N_USERS);
    int* cntH   = ialloc(N_ENT);
    int* offH   = ialloc(N_ENT + 1);
    int* curH   = ialloc(N_ENT);
    int* bsumU  = ialloc(256);
    int* bsxU   = ialloc(257);
    int* bsumH  = ialloc(256);
    int* bsxH   = ialloc(257);
    int* csr_tr = ialloc(NE);
    int* csr_it = ialloc(NEI);
    off += ioff;  // ints counted in float units (both 4B)
    // ---- union region (phases overlap) ----
    float* U = W + off;
    // phase A
    float* Uq = U;
    float* Ik = Uq + (size_t)N_USERS * D;
    float* Iv = Ik + (size_t)N_ITEMS * D;
    float* ex = Iv + (size_t)N_ITEMS * D;
    // phase B (overwrites A): pass1 EH+ET, pass2 PHI
    float* EH = U;
    float* ET = EH + (size_t)N_ENT * D;
    float* PHI = U;
    // phase C (overwrites B): double-buffered e_emb
    float* eA = U;
    float* eB = eA + (size_t)N_ENT * D;

    const int nbU = (N_USERS + 1023) / 1024;   // 49
    const int nbH = (N_ENT + 1023) / 1024;     // 98

    // ---- CSR build (histograms + scans; KG scatter deferred until alpha/eta) ----
    hipMemsetAsync(cntU, 0, N_USERS * 4, stream);
    hipMemsetAsync(cntH, 0, N_ENT * 4, stream);
    k_hist<<<(NEI + 255) / 256, 256, 0, stream>>>(inter_edge, cntU, NEI);
    k_hist<<<(NE + 255) / 256, 256, 0, stream>>>(edge_index, cntH, NE);
    k_scan1<<<nbU, 256, 0, stream>>>(cntU, offU, bsumU, N_USERS);
    k_scan2<<<1, 256, 0, stream>>>(bsumU, bsxU, nbU);
    k_scan3<<<(N_USERS + 256) / 256, 256, 0, stream>>>(offU, curU, bsxU, N_USERS, nbU);
    k_scan1<<<nbH, 256, 0, stream>>>(cntH, offH, bsumH, N_ENT);
    k_scan2<<<1, 256, 0, stream>>>(bsumH, bsxH, nbH);
    k_scan3<<<(N_ENT + 256) / 256, 256, 0, stream>>>(offH, curH, bsxH, N_ENT, nbH);
    k_scatterU<<<(NEI + 255) / 256, 256, 0, stream>>>(inter_edge, inter_edge_w, curU,
                                                      csr_it, csr_w, NEI);

    // ---- Phase A ----
    hipMemsetAsync(den, 0, N_USERS * 4, stream);
    hipMemsetAsync(c, 0, N_ITEMS * 4, stream);
    hipMemsetAsync(p, 0, 64 * 4, stream);
    k_proj_user<<<(N_USERS + 3) / 4, 256, 0, stream>>>(user_embed, Wq, Uq, N_USERS);
    k_proj_item<<<(N_ITEMS + 3) / 4, 256, 0, stream>>>(item_embed, Wk, Wv, Ik, Iv, N_ITEMS);
    k_scores_exp<<<(NEI + 3) / 4, 256, 0, stream>>>(inter_edge, inter_edge_w, Uq, Ik, ex, den, NEI);
    k_coef<<<(NEI + 255) / 256, 256, 0, stream>>>(inter_edge, ex, den, cntU, c, NEI);
    k_pdense<<<64, 256, 0, stream>>>(c, Iv, p, N_ITEMS);
    k_v2<<<1, 64, 0, stream>>>(rt_W2, rt_b2, p, v2, cb);

    // ---- Phase B ----
    k_ent_ab<<<(N_ENT / 4 + 3) / 4, 256, 0, stream>>>(ent_real, ent_imag, fp_W1, EH, ET, N_ENT);
    k_rel_tables<<<1, 64, 0, stream>>>(rel_real, rel_imag, fp_W1, rt_W1, RR1, PSI);
    k_omega1<<<(NE + 3) / 4, 256, 0, stream>>>(edge_index, edge_type, EH, ET, RR1,
                                               fp_b1, fp_W2, fp_b2, w0a, w1a, w2a, NE);
    k_ent_phi<<<(N_ENT / 4 + 3) / 4, 256, 0, stream>>>(ent_real, ent_imag, rt_W1, PHI, N_ENT);
    k_omega2<<<(NE + 3) / 4, 256, 0, stream>>>(edge_index, edge_type, PHI, PSI, rt_b1,
                                               v2, cb, w0a, w1a, w2a, omega, NE);

    // ---- graph prelims + KG CSR scatter ----
    hipMemsetAsync(seg_o, 0, N_ENT * 4, stream);
    hipMemsetAsync(seg_e, 0, N_ENT * 4, stream);
    k_sego<<<(NE + 255) / 256, 256, 0, stream>>>(edge_index, omega, seg_o, NE);
    k_alpha<<<(NE + 255) / 256, 256, 0, stream>>>(edge_index, omega, seg_o, alpha_g, seg_e, NE);
    k_scatterH<<<(NE + 255) / 256, 256, 0, stream>>>(edge_index, edge_type, alpha_g, seg_e,
                                                     curH, csr_tr, csr_a, csr_et, NE);

    // ---- init residuals + e_emb ----
    hipMemcpyAsync(out, entity_emb, (size_t)N_ENT * D * 4, hipMemcpyDeviceToDevice, stream);
    hipMemcpyAsync(out + (size_t)N_ENT * D, user_emb, (size_t)N_USERS * D * 4,
                   hipMemcpyDeviceToDevice, stream);
    hipMemcpyAsync(eA, entity_emb, (size_t)N_ENT * D * 4, hipMemcpyDeviceToDevice, stream);

    // ---- hops ----
    float* ecur = eA;
    float* enxt = eB;
    for (int hop = 1; hop <= 3; hop++) {
        int useEta = (hop == 3) ? 1 : 0;
        k_hop_e<<<(N_ENT + 3) / 4, 256, 0, stream>>>(offH, csr_tr, csr_a, csr_et, relation_emb,
                                                     ecur, enxt, out, useEta, N_ENT);
        k_hop_u<<<(N_USERS + 3) / 4, 256, 0, stream>>>(offU, csr_it, csr_w, ecur,
                                                       out + (size_t)N_ENT * D, N_USERS);
        float* tmp = ecur; ecur = enxt; enxt = tmp;
    }
}

// Round 3
// 1642.877 us; speedup vs baseline: 1.4705x; 1.1002x over previous
//
#include <hip/hip_runtime.h>
#include <hip/hip_bf16.h>
#include <math.h>

#define N_USERS 50000
#define N_ITEMS 30000
#define N_ENT   100000
#define NE      500000      // KG edges E
#define NEI     1000000     // interaction edges EI
#define D       64
#define GAMMA   0.2f

typedef __hip_bfloat16 bf16;

__device__ __forceinline__ float wave_sum(float v) {
    #pragma unroll
    for (int off = 32; off > 0; off >>= 1) v += __shfl_xor(v, off, 64);
    return v;
}

__device__ __forceinline__ float sigmoidf(float x) { return 1.0f / (1.0f + expf(-x)); }

__device__ __forceinline__ float n2n(float y) {
    if (isnan(y)) return 0.0f;
    if (isinf(y)) return y > 0.0f ? 1e4f : 1e-4f;
    return y;
}

// ================= CSR build =================
__global__ void k_hist(const int* __restrict__ idx, int* __restrict__ cnt, int n) {
    int e = blockIdx.x * blockDim.x + threadIdx.x;
    if (e < n) atomicAdd(&cnt[idx[e]], 1);
}

__global__ void k_scan1(const int* __restrict__ cnt, int* __restrict__ off,
                        int* __restrict__ bsum, int n) {
    __shared__ int sh[256];
    int t = threadIdx.x;
    int base = blockIdx.x * 1024 + t * 4;
    int v[4];
    #pragma unroll
    for (int j = 0; j < 4; j++) v[j] = (base + j < n) ? cnt[base + j] : 0;
    int tot = v[0] + v[1] + v[2] + v[3];
    sh[t] = tot;
    __syncthreads();
    for (int d = 1; d < 256; d <<= 1) {
        int x = (t >= d) ? sh[t - d] : 0;
        __syncthreads();
        sh[t] += x;
        __syncthreads();
    }
    int run = sh[t] - tot;
    #pragma unroll
    for (int j = 0; j < 4; j++) {
        if (base + j < n) off[base + j] = run;
        run += v[j];
    }
    if (t == 255) bsum[blockIdx.x] = sh[255];
}

__global__ void k_scan2(const int* __restrict__ bsum, int* __restrict__ bsx, int nb) {
    __shared__ int sh[256];
    int t = threadIdx.x;
    int v = (t < nb) ? bsum[t] : 0;
    sh[t] = v;
    __syncthreads();
    for (int d = 1; d < 256; d <<= 1) {
        int x = (t >= d) ? sh[t - d] : 0;
        __syncthreads();
        sh[t] += x;
        __syncthreads();
    }
    if (t < nb) bsx[t] = sh[t] - v;
    if (t == 255) bsx[nb] = sh[255];
}

__global__ void k_scan3(int* __restrict__ off, int* __restrict__ cur,
                        const int* __restrict__ bsx, int n, int nb) {
    int i = blockIdx.x * blockDim.x + threadIdx.x;
    if (i > n) return;
    int val = (i == n) ? bsx[nb] : off[i] + bsx[i >> 10];
    off[i] = val;
    if (i < n) cur[i] = val;
}

__global__ void k_scatterU(const int* __restrict__ ie, const float* __restrict__ w,
                           int* __restrict__ cur, int* __restrict__ csr_it,
                           float* __restrict__ csr_w, int n) {
    int e = blockIdx.x * blockDim.x + threadIdx.x;
    if (e >= n) return;
    int u = ie[e], it = ie[n + e];
    int pos = atomicAdd(&cur[u], 1);
    csr_it[pos] = it;
    csr_w[pos] = w[e];
}

// KG scatter: packed (t | r<<20) only
__global__ void k_scatterT(const int* __restrict__ eidx, const int* __restrict__ etype,
                           int* __restrict__ cur, int* __restrict__ csr_tr, int n) {
    int e = blockIdx.x * blockDim.x + threadIdx.x;
    if (e >= n) return;
    int h = eidx[e], t = eidx[n + e], r = etype[e] - 1;
    int pos = atomicAdd(&cur[h], 1);
    csr_tr[pos] = t | (r << 20);
}

// ================= Stage A =================
// Ik (bf16) = item@Wk, Iv (fp32) = item@Wv
__global__ void k_proj_item(const float* __restrict__ I, const float* __restrict__ Wk,
                            const float* __restrict__ Wv, bf16* __restrict__ IkB,
                            float* __restrict__ Iv, int n) {
    int gw = (blockIdx.x * blockDim.x + threadIdx.x) >> 6;
    int lane = threadIdx.x & 63;
    if (gw >= n) return;
    const float* row = I + (size_t)gw * D;
    float ak = 0.f, av = 0.f;
    #pragma unroll
    for (int k = 0; k < D; k++) {
        float x = row[k];
        ak += x * Wk[k * D + lane];
        av += x * Wv[k * D + lane];
    }
    IkB[(size_t)gw * D + lane] = __float2bfloat16(ak);
    Iv[(size_t)gw * D + lane] = av;
}

// wave per user: q = user_embed[u]@Wq in-register; per edge gather Ik, exp, den.
__global__ void k_userA(const int* __restrict__ offU, const int* __restrict__ csr_it,
                        const float* __restrict__ csr_w, const float* __restrict__ UE,
                        const float* __restrict__ Wq, const bf16* __restrict__ IkB,
                        float* __restrict__ exA, float* __restrict__ denU, int n) {
    int u = (blockIdx.x * blockDim.x + threadIdx.x) >> 6;
    int lane = threadIdx.x & 63;
    if (u >= n) return;
    int s = offU[u], e = offU[u + 1];
    if (s == e) return;
    float ue = UE[(size_t)u * D + lane];
    float q = 0.f;
    #pragma unroll
    for (int k = 0; k < D; k++) q += __shfl(ue, k, 64) * Wq[k * D + lane];
    float den = 0.f;
    for (int j = s; j < e; j++) {
        int it = csr_it[j];
        float ik = __bfloat162float(IkB[(size_t)it * D + lane]);
        float sc = wave_sum(q * ik);
        float ex = expf(sc * 0.125f * csr_w[j]);
        if (lane == 0) exA[j] = ex;
        den += ex;
    }
    if (lane == 0) denU[u] = den * (float)(e - s);  // den * deg (fused divisor)
}

// lane-parallel: c[it] += ex / (den*deg)
__global__ void k_userB(const int* __restrict__ offU, const int* __restrict__ csr_it,
                        const float* __restrict__ exA, const float* __restrict__ denU,
                        float* __restrict__ c, int n) {
    int u = (blockIdx.x * blockDim.x + threadIdx.x) >> 6;
    int lane = threadIdx.x & 63;
    if (u >= n) return;
    int s = offU[u], e = offU[u + 1];
    if (s == e) return;
    float inv = 1.0f / denU[u];
    for (int j = s + lane; j < e; j += 64)
        atomicAdd(&c[csr_it[j]], exA[j] * inv);
}

// p[d] = sum_i c[i] * Iv[i][d]
__global__ void k_pdense(const float* __restrict__ c, const float* __restrict__ Iv,
                         float* __restrict__ p, int n) {
    int lane = threadIdx.x & 63;
    int gw = blockIdx.x * 4 + (threadIdx.x >> 6);
    int nw = gridDim.x * 4;
    float acc = 0.f;
    for (int i = gw; i < n; i += nw) acc += c[i] * Iv[(size_t)i * D + lane];
    __shared__ float red[256];
    red[threadIdx.x] = acc;
    __syncthreads();
    if (threadIdx.x < 64) {
        float s = red[threadIdx.x] + red[threadIdx.x + 64] + red[threadIdx.x + 128] + red[threadIdx.x + 192];
        atomicAdd(&p[threadIdx.x], s);
    }
}

__global__ void k_v2(const float* __restrict__ rtW2, const float* __restrict__ rt_b2,
                     const float* __restrict__ p, float* __restrict__ v2, float* __restrict__ cb) {
    int j = threadIdx.x;  // 64 threads
    float acc = 0.f;
    #pragma unroll
    for (int k = 0; k < D; k++) acc += rtW2[j * D + k] * p[k];
    v2[j] = acc;
    float c = rt_b2[j] * p[j];
    c = wave_sum(c);
    if (j == 0) cb[0] = c;
}

// ================= Stage B =================
__global__ void k_ent_ab(const float* __restrict__ er, const float* __restrict__ ei,
                         const float* __restrict__ fpW1, float* __restrict__ EH,
                         float* __restrict__ ET, int n) {
    int gw = (blockIdx.x * blockDim.x + threadIdx.x) >> 6;
    int lane = threadIdx.x & 63;
    int u0 = gw * 4;
    if (u0 >= n) return;
    float aEH[4] = {0, 0, 0, 0}, aET[4] = {0, 0, 0, 0};
    for (int k = 0; k < 32; k++) {
        float w1a = fpW1[k * D + lane];
        float w1b = fpW1[(32 + k) * D + lane];
        float w1e = fpW1[(128 + k) * D + lane];
        float w1f = fpW1[(160 + k) * D + lane];
        #pragma unroll
        for (int q = 0; q < 4; q++) {
            int u = u0 + q;
            float sr = er[(size_t)u * 32 + k];
            float si = ei[(size_t)u * 32 + k];
            aEH[q] += sr * w1a + si * w1b;
            aET[q] += sr * w1e + si * w1f;
        }
    }
    #pragma unroll
    for (int q = 0; q < 4; q++) {
        int u = u0 + q;
        if (u < n) {
            EH[(size_t)u * D + lane] = aEH[q];
            ET[(size_t)u * D + lane] = aET[q];
        }
    }
}

__global__ void k_ent_phi(const float* __restrict__ er, const float* __restrict__ ei,
                          const float* __restrict__ rtW1, float* __restrict__ PHI, int n) {
    int gw = (blockIdx.x * blockDim.x + threadIdx.x) >> 6;
    int lane = threadIdx.x & 63;
    int u0 = gw * 4;
    if (u0 >= n) return;
    float aPH[4] = {0, 0, 0, 0};
    for (int k = 0; k < 32; k++) {
        float ra = rtW1[k * D + lane];
        float rb = rtW1[(32 + k) * D + lane];
        #pragma unroll
        for (int q = 0; q < 4; q++) {
            int u = u0 + q;
            aPH[q] += er[(size_t)u * 32 + k] * ra + ei[(size_t)u * 32 + k] * rb;
        }
    }
    #pragma unroll
    for (int q = 0; q < 4; q++) {
        int u = u0 + q;
        if (u < n) PHI[(size_t)u * D + lane] = aPH[q];
    }
}

__global__ void k_rel_tables(const float* __restrict__ rr, const float* __restrict__ ri,
                             const float* __restrict__ fpW1, const float* __restrict__ rtW1,
                             float* __restrict__ RR1, float* __restrict__ PSI) {
    int lane = threadIdx.x;  // 64
    for (int r = 0; r < 10; r++) {
        float a = 0.f, b = 0.f;
        for (int k = 0; k < 32; k++) {
            float sr = rr[r * 32 + k], si = ri[r * 32 + k];
            a += sr * fpW1[(64 + k) * D + lane] + si * fpW1[(96 + k) * D + lane];
            b += sr * rtW1[k * D + lane] + si * rtW1[(32 + k) * D + lane];
        }
        RR1[r * D + lane] = a;
        PSI[r * D + lane] = b;
    }
}

// wave per head h: EH[h] in regs, gather ET[t] per edge -> gate weights (csr order)
__global__ void k_omega1(const int* __restrict__ offH, const int* __restrict__ csr_tr,
                         const float* __restrict__ EH, const float* __restrict__ ET,
                         const float* __restrict__ RR1, const float* __restrict__ fp_b1,
                         const float* __restrict__ fpW2, const float* __restrict__ fp_b2,
                         float* __restrict__ w0a, float* __restrict__ w1a,
                         float* __restrict__ w2a, int n) {
    int h = (blockIdx.x * blockDim.x + threadIdx.x) >> 6;
    int lane = threadIdx.x & 63;
    if (h >= n) return;
    int s = offH[h], e = offH[h + 1];
    if (s == e) return;
    float ehh = EH[(size_t)h * D + lane] + fp_b1[lane];
    float f0 = fpW2[lane * 3 + 0], f1 = fpW2[lane * 3 + 1], f2 = fpW2[lane * 3 + 2];
    float b20 = fp_b2[0], b21 = fp_b2[1], b22 = fp_b2[2];
    for (int j = s; j < e; j++) {
        int pk = csr_tr[j];
        int t = pk & 0xFFFFF, r = pk >> 20;
        float z1 = sigmoidf(ehh + RR1[r * D + lane] + ET[(size_t)t * D + lane]);
        float a0 = wave_sum(z1 * f0) + b20;
        float a1 = wave_sum(z1 * f1) + b21;
        float a2 = wave_sum(z1 * f2) + b22;
        if (lane == 0) {
            float mx = fmaxf(a0, fmaxf(a1, a2));
            float e0 = expf(a0 - mx), e1 = expf(a1 - mx), e2 = expf(a2 - mx);
            float inv = 1.0f / (e0 + e1 + e2);
            w0a[j] = e0 * inv;
            w1a[j] = e1 * inv;
            w2a[j] = e2 * inv;
        }
    }
}

// wave per head h: omega per edge + local seg_o (no atomics)
__global__ void k_omega2a(const int* __restrict__ offH, const int* __restrict__ csr_tr,
                          const float* __restrict__ PHI, const float* __restrict__ PSI,
                          const float* __restrict__ rt_b1, const float* __restrict__ v2,
                          const float* __restrict__ cb, const float* __restrict__ w0a,
                          const float* __restrict__ w1a, const float* __restrict__ w2a,
                          float* __restrict__ omg, float* __restrict__ segO, int n) {
    int h = (blockIdx.x * blockDim.x + threadIdx.x) >> 6;
    int lane = threadIdx.x & 63;
    if (h >= n) return;
    int s = offH[h], e = offH[h + 1];
    if (s == e) return;
    float phh = PHI[(size_t)h * D + lane];
    float rb = rt_b1[lane], vv = v2[lane], cc = cb[0];
    float so = 0.f;
    for (int j = s; j < e; j++) {
        int pk = csr_tr[j];
        int t = pk & 0xFFFFF, r = pk >> 20;
        float t2 = w0a[j] * phh + w1a[j] * PSI[r * D + lane] +
                   w2a[j] * PHI[(size_t)t * D + lane] + rb;
        float om = (wave_sum(sigmoidf(t2) * vv) + cc) * 0.125f;
        if (lane == 0) omg[j] = om;
        so += om;
    }
    if (lane == 0) segO[h] = so;
}

// wave per head h: alpha, eta (normalized) lane-parallel
__global__ void k_omega2b(const int* __restrict__ offH, const float* __restrict__ omg,
                          const float* __restrict__ segO, float* __restrict__ csr_a,
                          float* __restrict__ csr_et, int n) {
    int h = (blockIdx.x * blockDim.x + threadIdx.x) >> 6;
    int lane = threadIdx.x & 63;
    if (h >= n) return;
    int s = offH[h], e = offH[h + 1];
    if (s == e) return;
    float invO = 1.0f / (segO[h] + 1e-8f);
    float se = 0.f;
    for (int j = s + lane; j < e; j += 64) {
        float a = omg[j] * invO;
        csr_a[j] = a;
        se += (a > GAMMA) ? a : 0.0f;
    }
    se = wave_sum(se);
    float invE = 1.0f / (se + 1e-8f);
    for (int j = s + lane; j < e; j += 64) {
        float a = csr_a[j];
        csr_et[j] = ((a > GAMMA) ? a : 0.0f) * invE;
    }
}

// ================= hops =================
__global__ void k_cvt(const float* __restrict__ src, bf16* __restrict__ dst, int n) {
    int i = blockIdx.x * blockDim.x + threadIdx.x;
    if (i < n) dst[i] = __float2bfloat16(src[i]);
}

__global__ void k_hop_e(const int* __restrict__ off, const int* __restrict__ tr,
                        const float* __restrict__ rho, const float* __restrict__ rel,
                        const bf16* __restrict__ ecur, bf16* __restrict__ enxt,
                        const float* __restrict__ initE, float* __restrict__ out,
                        int init, int n) {
    int gw = (blockIdx.x * blockDim.x + threadIdx.x) >> 6;
    int lane = threadIdx.x & 63;
    if (gw >= n) return;
    int s = off[gw], e = off[gw + 1];
    float acc = 0.f;
    for (int j = s; j < e; j++) {
        int pk = tr[j];
        acc += rho[j] * __bfloat162float(ecur[(size_t)(pk & 0xFFFFF) * D + lane]) *
               rel[(pk >> 20) * D + lane];
    }
    float x = acc / fmaxf((float)(e - s), 1.0f);
    float nrm = sqrtf(wave_sum(x * x));
    float y = n2n(x / fmaxf(nrm, 1e-8f));
    enxt[(size_t)gw * D + lane] = __float2bfloat16(y);
    size_t o = (size_t)gw * D + lane;
    out[o] = (init ? initE[o] : out[o]) + y;
}

__global__ void k_hop_u(const int* __restrict__ off, const int* __restrict__ itArr,
                        const float* __restrict__ wArr, const bf16* __restrict__ ecur,
                        const float* __restrict__ initU, float* __restrict__ out,
                        int init, int n) {
    int gw = (blockIdx.x * blockDim.x + threadIdx.x) >> 6;
    int lane = threadIdx.x & 63;
    if (gw >= n) return;
    int s = off[gw], e = off[gw + 1];
    float acc = 0.f;
    for (int j = s; j < e; j++)
        acc += wArr[j] * __bfloat162float(ecur[(size_t)itArr[j] * D + lane]);
    float nrm = sqrtf(wave_sum(acc * acc));
    float y = n2n(acc / fmaxf(nrm, 1e-8f));
    size_t o = (size_t)gw * D + lane;
    out[o] = (init ? initU[o] : out[o]) + y;
}

extern "C" void kernel_launch(void* const* d_in, const int* in_sizes, int n_in,
                              void* d_out, int out_size, void* d_ws, size_t ws_size,
                              hipStream_t stream) {
    const float* user_embed = (const float*)d_in[0];
    const float* item_embed = (const float*)d_in[1];
    const float* Wq = (const float*)d_in[2];
    const float* Wk = (const float*)d_in[3];
    const float* Wv = (const float*)d_in[4];
    const float* ent_real = (const float*)d_in[5];
    const float* ent_imag = (const float*)d_in[6];
    const float* rel_real = (const float*)d_in[7];
    const float* rel_imag = (const float*)d_in[8];
    const float* fp_W1 = (const float*)d_in[9];
    const float* fp_b1 = (const float*)d_in[10];
    const float* fp_W2 = (const float*)d_in[11];
    const float* fp_b2 = (const float*)d_in[12];
    const float* rt_W1 = (const float*)d_in[13];
    const float* rt_b1 = (const float*)d_in[14];
    const float* rt_W2 = (const float*)d_in[15];
    const float* rt_b2 = (const float*)d_in[16];
    const float* relation_emb = (const float*)d_in[17];
    const float* user_emb = (const float*)d_in[18];
    const float* entity_emb = (const float*)d_in[19];
    const float* inter_edge_w = (const float*)d_in[20];
    const int* edge_index = (const int*)d_in[21];
    const int* edge_type = (const int*)d_in[22];
    const int* inter_edge = (const int*)d_in[23];
    float* out = (float*)d_out;

    float* W = (float*)d_ws;
    size_t off = 0;
    auto alloc = [&](size_t n) { float* r = W + off; off += n; return r; };
    // persistent floats
    float* omg    = alloc(NE);
    float* w0a    = alloc(NE);
    float* w1a    = alloc(NE);
    float* w2a    = alloc(NE);
    float* segO   = alloc(N_ENT);
    float* denU   = alloc(N_USERS);
    float* c      = alloc(N_ITEMS);
    float* exA    = alloc(NEI);
    float* csr_a  = alloc(NE);
    float* csr_et = alloc(NE);
    float* csr_w  = alloc(NEI);
    float* p      = alloc(64);
    float* v2     = alloc(64);
    float* cb     = alloc(64);
    float* RR1    = alloc(10 * D);
    float* PSI    = alloc(10 * D);
    // persistent ints
    int* IW = (int*)(W + off);
    size_t ioff = 0;
    auto ialloc = [&](size_t n) { int* r = IW + ioff; ioff += n; return r; };
    int* cntU   = ialloc(N_USERS);
    int* offU   = ialloc(N_USERS + 1);
    int* curU   = ialloc(N_USERS);
    int* cntH   = ialloc(N_ENT);
    int* offH   = ialloc(N_ENT + 1);
    int* curH   = ialloc(N_ENT);
    int* bsumU  = ialloc(256);
    int* bsxU   = ialloc(257);
    int* bsumH  = ialloc(256);
    int* bsxH   = ialloc(257);
    int* csr_tr = ialloc(NE);
    int* csr_it = ialloc(NEI);
    off += ioff;
    // union region
    float* U = W + off;
    // phase A
    bf16*  IkB = (bf16*)U;
    float* Iv  = U + (size_t)N_ITEMS * 32;  // IkB is N_ITEMS*64*2B = N_ITEMS*32 floats
    // phase B
    float* EH  = U;
    float* ET  = EH + (size_t)N_ENT * D;
    float* PHI = U;                          // overwrites EH after k_omega1
    // phase C
    bf16* eA = (bf16*)U;
    bf16* eB = (bf16*)(U + (size_t)N_ENT * 32);

    const int nbU = (N_USERS + 1023) / 1024;
    const int nbH = (N_ENT + 1023) / 1024;

    // ---- CSR build ----
    hipMemsetAsync(cntU, 0, N_USERS * 4, stream);
    hipMemsetAsync(cntH, 0, N_ENT * 4, stream);
    k_hist<<<(NEI + 255) / 256, 256, 0, stream>>>(inter_edge, cntU, NEI);
    k_hist<<<(NE + 255) / 256, 256, 0, stream>>>(edge_index, cntH, NE);
    k_scan1<<<nbU, 256, 0, stream>>>(cntU, offU, bsumU, N_USERS);
    k_scan2<<<1, 256, 0, stream>>>(bsumU, bsxU, nbU);
    k_scan3<<<(N_USERS + 256) / 256, 256, 0, stream>>>(offU, curU, bsxU, N_USERS, nbU);
    k_scan1<<<nbH, 256, 0, stream>>>(cntH, offH, bsumH, N_ENT);
    k_scan2<<<1, 256, 0, stream>>>(bsumH, bsxH, nbH);
    k_scan3<<<(N_ENT + 256) / 256, 256, 0, stream>>>(offH, curH, bsxH, N_ENT, nbH);
    k_scatterU<<<(NEI + 255) / 256, 256, 0, stream>>>(inter_edge, inter_edge_w, curU,
                                                      csr_it, csr_w, NEI);
    k_scatterT<<<(NE + 255) / 256, 256, 0, stream>>>(edge_index, edge_type, curH, csr_tr, NE);

    // ---- Phase A ----
    hipMemsetAsync(c, 0, N_ITEMS * 4, stream);
    hipMemsetAsync(p, 0, 64 * 4, stream);
    k_proj_item<<<(N_ITEMS + 3) / 4, 256, 0, stream>>>(item_embed, Wk, Wv, IkB, Iv, N_ITEMS);
    k_userA<<<(N_USERS + 3) / 4, 256, 0, stream>>>(offU, csr_it, csr_w, user_embed, Wq,
                                                   IkB, exA, denU, N_USERS);
    k_userB<<<(N_USERS + 3) / 4, 256, 0, stream>>>(offU, csr_it, exA, denU, c, N_USERS);
    k_pdense<<<64, 256, 0, stream>>>(c, Iv, p, N_ITEMS);
    k_v2<<<1, 64, 0, stream>>>(rt_W2, rt_b2, p, v2, cb);

    // ---- Phase B ----
    k_ent_ab<<<(N_ENT / 4 + 3) / 4, 256, 0, stream>>>(ent_real, ent_imag, fp_W1, EH, ET, N_ENT);
    k_rel_tables<<<1, 64, 0, stream>>>(rel_real, rel_imag, fp_W1, rt_W1, RR1, PSI);
    k_omega1<<<(N_ENT + 3) / 4, 256, 0, stream>>>(offH, csr_tr, EH, ET, RR1, fp_b1,
                                                  fp_W2, fp_b2, w0a, w1a, w2a, N_ENT);
    k_ent_phi<<<(N_ENT / 4 + 3) / 4, 256, 0, stream>>>(ent_real, ent_imag, rt_W1, PHI, N_ENT);
    k_omega2a<<<(N_ENT + 3) / 4, 256, 0, stream>>>(offH, csr_tr, PHI, PSI, rt_b1, v2, cb,
                                                   w0a, w1a, w2a, omg, segO, N_ENT);
    k_omega2b<<<(N_ENT + 3) / 4, 256, 0, stream>>>(offH, omg, segO, csr_a, csr_et, N_ENT);

    // ---- hops ----
    k_cvt<<<(N_ENT * D + 255) / 256, 256, 0, stream>>>(entity_emb, eA, N_ENT * D);
    bf16* ecur = eA;
    bf16* enxt = eB;
    for (int hop = 1; hop <= 3; hop++) {
        const float* rho = (hop < 3) ? csr_a : csr_et;
        int init = (hop == 1) ? 1 : 0;
        k_hop_e<<<(N_ENT + 3) / 4, 256, 0, stream>>>(offH, csr_tr, rho, relation_emb,
                                                     ecur, enxt, entity_emb, out, init, N_ENT);
        k_hop_u<<<(N_USERS + 3) / 4, 256, 0, stream>>>(offU, csr_it, csr_w, ecur,
                                                       user_emb, out + (size_t)N_ENT * D,
                                                       init, N_USERS);
        bf16* tmp = ecur; ecur = enxt; enxt = tmp;
    }
}

// Round 4
// 1251.261 us; speedup vs baseline: 1.9307x; 1.3130x over previous
//
#include <hip/hip_runtime.h>
#include <hip/hip_bf16.h>
#include <math.h>

#define N_USERS 50000
#define N_ITEMS 30000
#define N_ENT   100000
#define NE      500000      // KG edges E
#define NEI     1000000     // interaction edges EI
#define D       64
#define GAMMA   0.2f

typedef __hip_bfloat16 bf16;

__device__ __forceinline__ float wave_sum(float v) {
    #pragma unroll
    for (int off = 32; off > 0; off >>= 1) v += __shfl_xor(v, off, 64);
    return v;
}

// sum within a 16-lane subgroup
__device__ __forceinline__ float g16_sum(float v) {
    #pragma unroll
    for (int off = 1; off < 16; off <<= 1) v += __shfl_xor(v, off, 64);
    return v;
}

__device__ __forceinline__ float bits2f(unsigned short u) {
    return __uint_as_float(((unsigned)u) << 16);
}

__device__ __forceinline__ float sigmoidf(float x) { return 1.0f / (1.0f + expf(-x)); }

__device__ __forceinline__ float n2n(float y) {
    if (isnan(y)) return 0.0f;
    if (isinf(y)) return y > 0.0f ? 1e4f : 1e-4f;
    return y;
}

// ================= CSR build =================
__global__ void k_hist(const int* __restrict__ idx, int* __restrict__ cnt, int n) {
    int e = blockIdx.x * blockDim.x + threadIdx.x;
    if (e < n) atomicAdd(&cnt[idx[e]], 1);
}

__global__ void k_scan1(const int* __restrict__ cnt, int* __restrict__ off,
                        int* __restrict__ bsum, int n) {
    __shared__ int sh[256];
    int t = threadIdx.x;
    int base = blockIdx.x * 1024 + t * 4;
    int v[4];
    #pragma unroll
    for (int j = 0; j < 4; j++) v[j] = (base + j < n) ? cnt[base + j] : 0;
    int tot = v[0] + v[1] + v[2] + v[3];
    sh[t] = tot;
    __syncthreads();
    for (int d = 1; d < 256; d <<= 1) {
        int x = (t >= d) ? sh[t - d] : 0;
        __syncthreads();
        sh[t] += x;
        __syncthreads();
    }
    int run = sh[t] - tot;
    #pragma unroll
    for (int j = 0; j < 4; j++) {
        if (base + j < n) off[base + j] = run;
        run += v[j];
    }
    if (t == 255) bsum[blockIdx.x] = sh[255];
}

__global__ void k_scan2(const int* __restrict__ bsum, int* __restrict__ bsx, int nb) {
    __shared__ int sh[256];
    int t = threadIdx.x;
    int v = (t < nb) ? bsum[t] : 0;
    sh[t] = v;
    __syncthreads();
    for (int d = 1; d < 256; d <<= 1) {
        int x = (t >= d) ? sh[t - d] : 0;
        __syncthreads();
        sh[t] += x;
        __syncthreads();
    }
    if (t < nb) bsx[t] = sh[t] - v;
    if (t == 255) bsx[nb] = sh[255];
}

__global__ void k_scan3(int* __restrict__ off, int* __restrict__ cur,
                        const int* __restrict__ bsx, int n, int nb) {
    int i = blockIdx.x * blockDim.x + threadIdx.x;
    if (i > n) return;
    int val = (i == n) ? bsx[nb] : off[i] + bsx[i >> 10];
    off[i] = val;
    if (i < n) cur[i] = val;
}

__global__ void k_scatterU(const int* __restrict__ ie, const float* __restrict__ w,
                           int* __restrict__ cur, int* __restrict__ csr_it,
                           float* __restrict__ csr_w, int n) {
    int e = blockIdx.x * blockDim.x + threadIdx.x;
    if (e >= n) return;
    int u = ie[e], it = ie[n + e];
    int pos = atomicAdd(&cur[u], 1);
    csr_it[pos] = it;
    csr_w[pos] = w[e];
}

__global__ void k_scatterT(const int* __restrict__ eidx, const int* __restrict__ etype,
                           int* __restrict__ cur, int* __restrict__ csr_tr, int n) {
    int e = blockIdx.x * blockDim.x + threadIdx.x;
    if (e >= n) return;
    int h = eidx[e], t = eidx[n + e], r = etype[e] - 1;
    int pos = atomicAdd(&cur[h], 1);
    csr_tr[pos] = t | (r << 20);
}

// ================= Stage A =================
__global__ void k_proj_user(const float* __restrict__ U, const float* __restrict__ Wq,
                            float* __restrict__ Uq, int n) {
    int gw = (blockIdx.x * blockDim.x + threadIdx.x) >> 6;
    int lane = threadIdx.x & 63;
    if (gw >= n) return;
    const float* row = U + (size_t)gw * D;
    float acc = 0.f;
    #pragma unroll
    for (int k = 0; k < D; k++) acc += row[k] * Wq[k * D + lane];
    Uq[(size_t)gw * D + lane] = acc;
}

__global__ void k_proj_item(const float* __restrict__ I, const float* __restrict__ Wk,
                            const float* __restrict__ Wv, bf16* __restrict__ IkB,
                            float* __restrict__ Iv, int n) {
    int gw = (blockIdx.x * blockDim.x + threadIdx.x) >> 6;
    int lane = threadIdx.x & 63;
    if (gw >= n) return;
    const float* row = I + (size_t)gw * D;
    float ak = 0.f, av = 0.f;
    #pragma unroll
    for (int k = 0; k < D; k++) {
        float x = row[k];
        ak += x * Wk[k * D + lane];
        av += x * Wv[k * D + lane];
    }
    IkB[(size_t)gw * D + lane] = __float2bfloat16(ak);
    Iv[(size_t)gw * D + lane] = av;
}

// wave/user, 16-lane subgroups, 4 edges in flight
__global__ void k_userA(const int* __restrict__ offU, const int* __restrict__ csr_it,
                        const float* __restrict__ csr_w, const float* __restrict__ Uq,
                        const bf16* __restrict__ IkB, float* __restrict__ exA,
                        float* __restrict__ denU, int n) {
    int u = (blockIdx.x * blockDim.x + threadIdx.x) >> 6;
    int lane = threadIdx.x & 63;
    if (u >= n) return;
    int s = offU[u], e = offU[u + 1];
    if (s == e) return;
    int l = lane & 15, g = lane >> 4;
    float4 qv = *(const float4*)&Uq[(size_t)u * D + l * 4];
    float den = 0.f;
    for (int j0 = s; j0 < e; j0 += 4) {
        int j = j0 + g;
        bool valid = j < e;
        int jj = valid ? j : s;
        int it = csr_it[jj];
        ushort4 ik = *(const ushort4*)&IkB[(size_t)it * D + l * 4];
        float d = qv.x * bits2f(ik.x) + qv.y * bits2f(ik.y) +
                  qv.z * bits2f(ik.z) + qv.w * bits2f(ik.w);
        float sc = g16_sum(d);
        float ex = valid ? expf(sc * 0.125f * csr_w[jj]) : 0.f;
        den += ex;
        if (valid && l == 0) exA[j] = ex;
    }
    den += __shfl_xor(den, 16, 64);
    den += __shfl_xor(den, 32, 64);
    if (lane == 0) denU[u] = den * (float)(e - s);  // den * deg
}

__global__ void k_userB(const int* __restrict__ offU, const int* __restrict__ csr_it,
                        const float* __restrict__ exA, const float* __restrict__ denU,
                        float* __restrict__ c, int n) {
    int u = (blockIdx.x * blockDim.x + threadIdx.x) >> 6;
    int lane = threadIdx.x & 63;
    if (u >= n) return;
    int s = offU[u], e = offU[u + 1];
    if (s == e) return;
    float inv = 1.0f / denU[u];
    for (int j = s + lane; j < e; j += 64)
        atomicAdd(&c[csr_it[j]], exA[j] * inv);
}

__global__ void k_pdense(const float* __restrict__ c, const float* __restrict__ Iv,
                         float* __restrict__ p, int n) {
    int lane = threadIdx.x & 63;
    int gw = blockIdx.x * 4 + (threadIdx.x >> 6);
    int nw = gridDim.x * 4;
    float acc = 0.f;
    for (int i = gw; i < n; i += nw) acc += c[i] * Iv[(size_t)i * D + lane];
    __shared__ float red[256];
    red[threadIdx.x] = acc;
    __syncthreads();
    if (threadIdx.x < 64) {
        float s = red[threadIdx.x] + red[threadIdx.x + 64] + red[threadIdx.x + 128] + red[threadIdx.x + 192];
        atomicAdd(&p[threadIdx.x], s);
    }
}

__global__ void k_v2(const float* __restrict__ rtW2, const float* __restrict__ rt_b2,
                     const float* __restrict__ p, float* __restrict__ v2, float* __restrict__ cb) {
    int j = threadIdx.x;  // 64 threads
    float acc = 0.f;
    #pragma unroll
    for (int k = 0; k < D; k++) acc += rtW2[j * D + k] * p[k];
    v2[j] = acc;
    float c = rt_b2[j] * p[j];
    c = wave_sum(c);
    if (j == 0) cb[0] = c;
}

// ================= Stage B =================
__global__ void k_ent_ab(const float* __restrict__ er, const float* __restrict__ ei,
                         const float* __restrict__ fpW1, float* __restrict__ EH,
                         float* __restrict__ ET, int n) {
    int gw = (blockIdx.x * blockDim.x + threadIdx.x) >> 6;
    int lane = threadIdx.x & 63;
    int u0 = gw * 4;
    if (u0 >= n) return;
    float aEH[4] = {0, 0, 0, 0}, aET[4] = {0, 0, 0, 0};
    for (int k = 0; k < 32; k++) {
        float w1a = fpW1[k * D + lane];
        float w1b = fpW1[(32 + k) * D + lane];
        float w1e = fpW1[(128 + k) * D + lane];
        float w1f = fpW1[(160 + k) * D + lane];
        #pragma unroll
        for (int q = 0; q < 4; q++) {
            int u = u0 + q;
            float sr = er[(size_t)u * 32 + k];
            float si = ei[(size_t)u * 32 + k];
            aEH[q] += sr * w1a + si * w1b;
            aET[q] += sr * w1e + si * w1f;
        }
    }
    #pragma unroll
    for (int q = 0; q < 4; q++) {
        int u = u0 + q;
        if (u < n) {
            EH[(size_t)u * D + lane] = aEH[q];
            ET[(size_t)u * D + lane] = aET[q];
        }
    }
}

__global__ void k_ent_phi(const float* __restrict__ er, const float* __restrict__ ei,
                          const float* __restrict__ rtW1, float* __restrict__ PHI, int n) {
    int gw = (blockIdx.x * blockDim.x + threadIdx.x) >> 6;
    int lane = threadIdx.x & 63;
    int u0 = gw * 4;
    if (u0 >= n) return;
    float aPH[4] = {0, 0, 0, 0};
    for (int k = 0; k < 32; k++) {
        float ra = rtW1[k * D + lane];
        float rb = rtW1[(32 + k) * D + lane];
        #pragma unroll
        for (int q = 0; q < 4; q++) {
            int u = u0 + q;
            aPH[q] += er[(size_t)u * 32 + k] * ra + ei[(size_t)u * 32 + k] * rb;
        }
    }
    #pragma unroll
    for (int q = 0; q < 4; q++) {
        int u = u0 + q;
        if (u < n) PHI[(size_t)u * D + lane] = aPH[q];
    }
}

__global__ void k_rel_tables(const float* __restrict__ rr, const float* __restrict__ ri,
                             const float* __restrict__ fpW1, const float* __restrict__ rtW1,
                             float* __restrict__ RR1, float* __restrict__ PSI) {
    int lane = threadIdx.x;  // 64
    for (int r = 0; r < 10; r++) {
        float a = 0.f, b = 0.f;
        for (int k = 0; k < 32; k++) {
            float sr = rr[r * 32 + k], si = ri[r * 32 + k];
            a += sr * fpW1[(64 + k) * D + lane] + si * fpW1[(96 + k) * D + lane];
            b += sr * rtW1[k * D + lane] + si * rtW1[(32 + k) * D + lane];
        }
        RR1[r * D + lane] = a;
        PSI[r * D + lane] = b;
    }
}

// wave/head, 16-lane subgroups, 4 edges in flight: gate weights
__global__ void k_omega1(const int* __restrict__ offH, const int* __restrict__ csr_tr,
                         const float* __restrict__ EH, const float* __restrict__ ET,
                         const float* __restrict__ RR1, const float* __restrict__ fp_b1,
                         const float* __restrict__ fpW2, const float* __restrict__ fp_b2,
                         float* __restrict__ w0a, float* __restrict__ w1a,
                         float* __restrict__ w2a, int n) {
    int h = (blockIdx.x * blockDim.x + threadIdx.x) >> 6;
    int lane = threadIdx.x & 63;
    if (h >= n) return;
    int s = offH[h], e = offH[h + 1];
    if (s == e) return;
    int l = lane & 15, g = lane >> 4;
    int d0 = l * 4;
    float4 ehh = *(const float4*)&EH[(size_t)h * D + d0];
    float4 b1 = *(const float4*)&fp_b1[d0];
    ehh.x += b1.x; ehh.y += b1.y; ehh.z += b1.z; ehh.w += b1.w;
    float f0[4], f1[4], f2[4];
    #pragma unroll
    for (int cc = 0; cc < 4; cc++) {
        f0[cc] = fpW2[(d0 + cc) * 3 + 0];
        f1[cc] = fpW2[(d0 + cc) * 3 + 1];
        f2[cc] = fpW2[(d0 + cc) * 3 + 2];
    }
    float b20 = fp_b2[0], b21 = fp_b2[1], b22 = fp_b2[2];
    for (int j0 = s; j0 < e; j0 += 4) {
        int j = j0 + g;
        bool valid = j < e;
        int jj = valid ? j : s;
        int pk = csr_tr[jj];
        int t = pk & 0xFFFFF, r = pk >> 20;
        float4 et = *(const float4*)&ET[(size_t)t * D + d0];
        float4 rr = *(const float4*)&RR1[r * D + d0];
        float z0 = sigmoidf(ehh.x + rr.x + et.x);
        float z1 = sigmoidf(ehh.y + rr.y + et.y);
        float z2 = sigmoidf(ehh.z + rr.z + et.z);
        float z3 = sigmoidf(ehh.w + rr.w + et.w);
        float a0 = z0 * f0[0] + z1 * f0[1] + z2 * f0[2] + z3 * f0[3];
        float a1 = z0 * f1[0] + z1 * f1[1] + z2 * f1[2] + z3 * f1[3];
        float a2 = z0 * f2[0] + z1 * f2[1] + z2 * f2[2] + z3 * f2[3];
        a0 = g16_sum(a0); a1 = g16_sum(a1); a2 = g16_sum(a2);
        if (valid && l == 0) {
            a0 += b20; a1 += b21; a2 += b22;
            float mx = fmaxf(a0, fmaxf(a1, a2));
            float e0 = expf(a0 - mx), e1 = expf(a1 - mx), e2 = expf(a2 - mx);
            float inv = 1.0f / (e0 + e1 + e2);
            w0a[j] = e0 * inv;
            w1a[j] = e1 * inv;
            w2a[j] = e2 * inv;
        }
    }
}

// wave/head, subgroups: omega + local seg_o
__global__ void k_omega2a(const int* __restrict__ offH, const int* __restrict__ csr_tr,
                          const float* __restrict__ PHI, const float* __restrict__ PSI,
                          const float* __restrict__ rt_b1, const float* __restrict__ v2,
                          const float* __restrict__ cb, const float* __restrict__ w0a,
                          const float* __restrict__ w1a, const float* __restrict__ w2a,
                          float* __restrict__ omg, float* __restrict__ segO, int n) {
    int h = (blockIdx.x * blockDim.x + threadIdx.x) >> 6;
    int lane = threadIdx.x & 63;
    if (h >= n) return;
    int s = offH[h], e = offH[h + 1];
    if (s == e) return;
    int l = lane & 15, g = lane >> 4;
    int d0 = l * 4;
    float4 phh = *(const float4*)&PHI[(size_t)h * D + d0];
    float4 rb = *(const float4*)&rt_b1[d0];
    float4 vv = *(const float4*)&v2[d0];
    float cc = cb[0];
    float so = 0.f;
    for (int j0 = s; j0 < e; j0 += 4) {
        int j = j0 + g;
        bool valid = j < e;
        int jj = valid ? j : s;
        int pk = csr_tr[jj];
        int t = pk & 0xFFFFF, r = pk >> 20;
        float W0 = w0a[jj], W1 = w1a[jj], W2 = w2a[jj];
        float4 pt = *(const float4*)&PHI[(size_t)t * D + d0];
        float4 ps = *(const float4*)&PSI[r * D + d0];
        float sv = sigmoidf(W0 * phh.x + W1 * ps.x + W2 * pt.x + rb.x) * vv.x
                 + sigmoidf(W0 * phh.y + W1 * ps.y + W2 * pt.y + rb.y) * vv.y
                 + sigmoidf(W0 * phh.z + W1 * ps.z + W2 * pt.z + rb.z) * vv.z
                 + sigmoidf(W0 * phh.w + W1 * ps.w + W2 * pt.w + rb.w) * vv.w;
        sv = g16_sum(sv);
        float om = (sv + cc) * 0.125f;
        if (valid) {
            if (l == 0) omg[j] = om;
            so += om;
        }
    }
    so += __shfl_xor(so, 16, 64);
    so += __shfl_xor(so, 32, 64);
    if (lane == 0) segO[h] = so;
}

__global__ void k_omega2b(const int* __restrict__ offH, const float* __restrict__ omg,
                          const float* __restrict__ segO, float* __restrict__ csr_a,
                          float* __restrict__ csr_et, int n) {
    int h = (blockIdx.x * blockDim.x + threadIdx.x) >> 6;
    int lane = threadIdx.x & 63;
    if (h >= n) return;
    int s = offH[h], e = offH[h + 1];
    if (s == e) return;
    float invO = 1.0f / (segO[h] + 1e-8f);
    float se = 0.f;
    for (int j = s + lane; j < e; j += 64) {
        float a = omg[j] * invO;
        csr_a[j] = a;
        se += (a > GAMMA) ? a : 0.0f;
    }
    se = wave_sum(se);
    float invE = 1.0f / (se + 1e-8f);
    for (int j = s + lane; j < e; j += 64) {
        float a = csr_a[j];
        csr_et[j] = ((a > GAMMA) ? a : 0.0f) * invE;
    }
}

// ================= hops =================
__global__ void k_cvt(const float* __restrict__ src, bf16* __restrict__ dst, int n) {
    int i = blockIdx.x * blockDim.x + threadIdx.x;
    if (i < n) dst[i] = __float2bfloat16(src[i]);
}

__global__ void k_hop_e(const int* __restrict__ off, const int* __restrict__ tr,
                        const float* __restrict__ rho, const float* __restrict__ rel,
                        const bf16* __restrict__ ecur, bf16* __restrict__ enxt,
                        const float* __restrict__ initE, float* __restrict__ out,
                        int init, int n) {
    int gw = (blockIdx.x * blockDim.x + threadIdx.x) >> 6;
    int lane = threadIdx.x & 63;
    if (gw >= n) return;
    int s = off[gw], e = off[gw + 1];
    int l = lane & 15, g = lane >> 4;
    int d0 = l * 4;
    float a0 = 0.f, a1 = 0.f, a2 = 0.f, a3 = 0.f;
    for (int j0 = s; j0 < e; j0 += 4) {
        int j = j0 + g;
        bool valid = j < e;
        int jj = valid ? j : s;
        int pk = tr[jj];
        int t = pk & 0xFFFFF, r = pk >> 20;
        float rh = valid ? rho[jj] : 0.f;
        ushort4 ev = *(const ushort4*)&ecur[(size_t)t * D + d0];
        float4 rl = *(const float4*)&rel[r * D + d0];
        a0 += rh * bits2f(ev.x) * rl.x;
        a1 += rh * bits2f(ev.y) * rl.y;
        a2 += rh * bits2f(ev.z) * rl.z;
        a3 += rh * bits2f(ev.w) * rl.w;
    }
    // combine across the 4 subgroups (all groups end with identical totals)
    a0 += __shfl_xor(a0, 16, 64); a0 += __shfl_xor(a0, 32, 64);
    a1 += __shfl_xor(a1, 16, 64); a1 += __shfl_xor(a1, 32, 64);
    a2 += __shfl_xor(a2, 16, 64); a2 += __shfl_xor(a2, 32, 64);
    a3 += __shfl_xor(a3, 16, 64); a3 += __shfl_xor(a3, 32, 64);
    float invd = 1.0f / fmaxf((float)(e - s), 1.0f);
    a0 *= invd; a1 *= invd; a2 *= invd; a3 *= invd;
    float ss = a0 * a0 + a1 * a1 + a2 * a2 + a3 * a3;
    ss = g16_sum(ss);
    float nrm = fmaxf(sqrtf(ss), 1e-8f);
    float y0 = n2n(a0 / nrm), y1 = n2n(a1 / nrm), y2 = n2n(a2 / nrm), y3 = n2n(a3 / nrm);
    if (g == 0) {
        ushort4 st;
        st.x = (unsigned short)(__float_as_uint(__bfloat162float(__float2bfloat16(y0))) >> 16);
        st.x = (unsigned short)(__float_as_uint(y0 + 0.0f) >> 16);  // overwritten below by proper cvt
        // proper bf16 round-to-nearest via intrinsic:
        bf16 b0 = __float2bfloat16(y0), b1 = __float2bfloat16(y1),
             b2 = __float2bfloat16(y2), b3 = __float2bfloat16(y3);
        bf16* dst = enxt + (size_t)gw * D + d0;
        dst[0] = b0; dst[1] = b1; dst[2] = b2; dst[3] = b3;
        size_t o = (size_t)gw * D + d0;
        float4 prev;
        if (init) prev = *(const float4*)&initE[o];
        else      prev = *(const float4*)&out[o];
        float4 res = make_float4(prev.x + y0, prev.y + y1, prev.z + y2, prev.w + y3);
        *(float4*)&out[o] = res;
    }
}

__global__ void k_hop_u(const int* __restrict__ off, const int* __restrict__ itArr,
                        const float* __restrict__ wArr, const bf16* __restrict__ ecur,
                        const float* __restrict__ initU, float* __restrict__ out,
                        int init, int n) {
    int gw = (blockIdx.x * blockDim.x + threadIdx.x) >> 6;
    int lane = threadIdx.x & 63;
    if (gw >= n) return;
    int s = off[gw], e = off[gw + 1];
    int l = lane & 15, g = lane >> 4;
    int d0 = l * 4;
    float a0 = 0.f, a1 = 0.f, a2 = 0.f, a3 = 0.f;
    for (int j0 = s; j0 < e; j0 += 4) {
        int j = j0 + g;
        bool valid = j < e;
        int jj = valid ? j : s;
        int it = itArr[jj];
        float w = valid ? wArr[jj] : 0.f;
        ushort4 ev = *(const ushort4*)&ecur[(size_t)it * D + d0];
        a0 += w * bits2f(ev.x);
        a1 += w * bits2f(ev.y);
        a2 += w * bits2f(ev.z);
        a3 += w * bits2f(ev.w);
    }
    a0 += __shfl_xor(a0, 16, 64); a0 += __shfl_xor(a0, 32, 64);
    a1 += __shfl_xor(a1, 16, 64); a1 += __shfl_xor(a1, 32, 64);
    a2 += __shfl_xor(a2, 16, 64); a2 += __shfl_xor(a2, 32, 64);
    a3 += __shfl_xor(a3, 16, 64); a3 += __shfl_xor(a3, 32, 64);
    float ss = a0 * a0 + a1 * a1 + a2 * a2 + a3 * a3;
    ss = g16_sum(ss);
    float nrm = fmaxf(sqrtf(ss), 1e-8f);
    float y0 = n2n(a0 / nrm), y1 = n2n(a1 / nrm), y2 = n2n(a2 / nrm), y3 = n2n(a3 / nrm);
    if (g == 0) {
        size_t o = (size_t)gw * D + d0;
        float4 prev;
        if (init) prev = *(const float4*)&initU[o];
        else      prev = *(const float4*)&out[o];
        float4 res = make_float4(prev.x + y0, prev.y + y1, prev.z + y2, prev.w + y3);
        *(float4*)&out[o] = res;
    }
}

extern "C" void kernel_launch(void* const* d_in, const int* in_sizes, int n_in,
                              void* d_out, int out_size, void* d_ws, size_t ws_size,
                              hipStream_t stream) {
    const float* user_embed = (const float*)d_in[0];
    const float* item_embed = (const float*)d_in[1];
    const float* Wq = (const float*)d_in[2];
    const float* Wk = (const float*)d_in[3];
    const float* Wv = (const float*)d_in[4];
    const float* ent_real = (const float*)d_in[5];
    const float* ent_imag = (const float*)d_in[6];
    const float* rel_real = (const float*)d_in[7];
    const float* rel_imag = (const float*)d_in[8];
    const float* fp_W1 = (const float*)d_in[9];
    const float* fp_b1 = (const float*)d_in[10];
    const float* fp_W2 = (const float*)d_in[11];
    const float* fp_b2 = (const float*)d_in[12];
    const float* rt_W1 = (const float*)d_in[13];
    const float* rt_b1 = (const float*)d_in[14];
    const float* rt_W2 = (const float*)d_in[15];
    const float* rt_b2 = (const float*)d_in[16];
    const float* relation_emb = (const float*)d_in[17];
    const float* user_emb = (const float*)d_in[18];
    const float* entity_emb = (const float*)d_in[19];
    const float* inter_edge_w = (const float*)d_in[20];
    const int* edge_index = (const int*)d_in[21];
    const int* edge_type = (const int*)d_in[22];
    const int* inter_edge = (const int*)d_in[23];
    float* out = (float*)d_out;

    float* W = (float*)d_ws;
    size_t off = 0;
    auto alloc = [&](size_t n) { float* r = W + off; off += n; return r; };
    // persistent floats
    float* omg    = alloc(NE);
    float* w0a    = alloc(NE);
    float* w1a    = alloc(NE);
    float* w2a    = alloc(NE);
    float* segO   = alloc(N_ENT);
    float* denU   = alloc(N_USERS);
    float* c      = alloc(N_ITEMS);
    float* exA    = alloc(NEI);
    float* csr_a  = alloc(NE);
    float* csr_et = alloc(NE);
    float* csr_w  = alloc(NEI);
    float* p      = alloc(64);
    float* v2     = alloc(64);
    float* cb     = alloc(64);
    float* RR1    = alloc(10 * D);
    float* PSI    = alloc(10 * D);
    // persistent ints
    int* IW = (int*)(W + off);
    size_t ioff = 0;
    auto ialloc = [&](size_t n) { int* r = IW + ioff; ioff += n; return r; };
    int* cntU   = ialloc(N_USERS);
    int* offU   = ialloc(N_USERS + 1);
    int* curU   = ialloc(N_USERS);
    int* cntH   = ialloc(N_ENT);
    int* offH   = ialloc(N_ENT + 1);
    int* curH   = ialloc(N_ENT);
    int* bsumU  = ialloc(256);
    int* bsxU   = ialloc(257);
    int* bsumH  = ialloc(256);
    int* bsxH   = ialloc(257);
    int* csr_tr = ialloc(NE);
    int* csr_it = ialloc(NEI);
    off += ioff;
    // union region
    float* U = W + off;
    // phase A
    bf16*  IkB = (bf16*)U;
    float* Iv  = U + (size_t)N_ITEMS * 32;
    float* Uq  = Iv + (size_t)N_ITEMS * D;
    // phase B
    float* EH  = U;
    float* ET  = EH + (size_t)N_ENT * D;
    float* PHI = U;                          // overwrites EH after k_omega1
    // phase C
    bf16* eA = (bf16*)U;
    bf16* eB = (bf16*)(U + (size_t)N_ENT * 32);

    const int nbU = (N_USERS + 1023) / 1024;
    const int nbH = (N_ENT + 1023) / 1024;

    // ---- CSR build ----
    hipMemsetAsync(cntU, 0, N_USERS * 4, stream);
    hipMemsetAsync(cntH, 0, N_ENT * 4, stream);
    k_hist<<<(NEI + 255) / 256, 256, 0, stream>>>(inter_edge, cntU, NEI);
    k_hist<<<(NE + 255) / 256, 256, 0, stream>>>(edge_index, cntH, NE);
    k_scan1<<<nbU, 256, 0, stream>>>(cntU, offU, bsumU, N_USERS);
    k_scan2<<<1, 256, 0, stream>>>(bsumU, bsxU, nbU);
    k_scan3<<<(N_USERS + 256) / 256, 256, 0, stream>>>(offU, curU, bsxU, N_USERS, nbU);
    k_scan1<<<nbH, 256, 0, stream>>>(cntH, offH, bsumH, N_ENT);
    k_scan2<<<1, 256, 0, stream>>>(bsumH, bsxH, nbH);
    k_scan3<<<(N_ENT + 256) / 256, 256, 0, stream>>>(offH, curH, bsxH, N_ENT, nbH);
    k_scatterU<<<(NEI + 255) / 256, 256, 0, stream>>>(inter_edge, inter_edge_w, curU,
                                                      csr_it, csr_w, NEI);
    k_scatterT<<<(NE + 255) / 256, 256, 0, stream>>>(edge_index, edge_type, curH, csr_tr, NE);

    // ---- Phase A ----
    hipMemsetAsync(c, 0, N_ITEMS * 4, stream);
    hipMemsetAsync(p, 0, 64 * 4, stream);
    k_proj_item<<<(N_ITEMS + 3) / 4, 256, 0, stream>>>(item_embed, Wk, Wv, IkB, Iv, N_ITEMS);
    k_proj_user<<<(N_USERS + 3) / 4, 256, 0, stream>>>(user_embed, Wq, Uq, N_USERS);
    k_userA<<<(N_USERS + 3) / 4, 256, 0, stream>>>(offU, csr_it, csr_w, Uq, IkB,
                                                   exA, denU, N_USERS);
    k_userB<<<(N_USERS + 3) / 4, 256, 0, stream>>>(offU, csr_it, exA, denU, c, N_USERS);
    k_pdense<<<64, 256, 0, stream>>>(c, Iv, p, N_ITEMS);
    k_v2<<<1, 64, 0, stream>>>(rt_W2, rt_b2, p, v2, cb);

    // ---- Phase B ----
    k_ent_ab<<<(N_ENT / 4 + 3) / 4, 256, 0, stream>>>(ent_real, ent_imag, fp_W1, EH, ET, N_ENT);
    k_rel_tables<<<1, 64, 0, stream>>>(rel_real, rel_imag, fp_W1, rt_W1, RR1, PSI);
    k_omega1<<<(N_ENT + 3) / 4, 256, 0, stream>>>(offH, csr_tr, EH, ET, RR1, fp_b1,
                                                  fp_W2, fp_b2, w0a, w1a, w2a, N_ENT);
    k_ent_phi<<<(N_ENT / 4 + 3) / 4, 256, 0, stream>>>(ent_real, ent_imag, rt_W1, PHI, N_ENT);
    k_omega2a<<<(N_ENT + 3) / 4, 256, 0, stream>>>(offH, csr_tr, PHI, PSI, rt_b1, v2, cb,
                                                   w0a, w1a, w2a, omg, segO, N_ENT);
    k_omega2b<<<(N_ENT + 3) / 4, 256, 0, stream>>>(offH, omg, segO, csr_a, csr_et, N_ENT);

    // ---- hops ----
    k_cvt<<<(N_ENT * D + 255) / 256, 256, 0, stream>>>(entity_emb, eA, N_ENT * D);
    bf16* ecur = eA;
    bf16* enxt = eB;
    for (int hop = 1; hop <= 3; hop++) {
        const float* rho = (hop < 3) ? csr_a : csr_et;
        int init = (hop == 1) ? 1 : 0;
        k_hop_e<<<(N_ENT + 3) / 4, 256, 0, stream>>>(offH, csr_tr, rho, relation_emb,
                                                     ecur, enxt, entity_emb, out, init, N_ENT);
        k_hop_u<<<(N_USERS + 3) / 4, 256, 0, stream>>>(offU, csr_it, csr_w, ecur,
                                                       user_emb, out + (size_t)N_ENT * D,
                                                       init, N_USERS);
        bf16* tmp = ecur; ecur = enxt; enxt = tmp;
    }
}

// Round 5
// 1003.805 us; speedup vs baseline: 2.4066x; 1.2465x over previous
//
#include <hip/hip_runtime.h>
#include <hip/hip_bf16.h>
#include <math.h>

#define N_USERS 50000
#define N_ITEMS 30000
#define N_ENT   100000
#define NE      500000      // KG edges E
#define NEI     1000000     // interaction edges EI
#define D       64
#define GAMMA   0.2f

typedef __hip_bfloat16 bf16;

__device__ __forceinline__ float wave_sum(float v) {
    #pragma unroll
    for (int off = 32; off > 0; off >>= 1) v += __shfl_xor(v, off, 64);
    return v;
}

// sum within a 16-lane subgroup
__device__ __forceinline__ float g16_sum(float v) {
    #pragma unroll
    for (int off = 1; off < 16; off <<= 1) v += __shfl_xor(v, off, 64);
    return v;
}

__device__ __forceinline__ float bits2f(unsigned short u) {
    return __uint_as_float(((unsigned)u) << 16);
}

__device__ __forceinline__ unsigned short f2bf_bits(float f) {
    bf16 b = __float2bfloat16(f);
    return *(unsigned short*)&b;
}

__device__ __forceinline__ float sigmoidf(float x) { return 1.0f / (1.0f + expf(-x)); }

__device__ __forceinline__ float n2n(float y) {
    if (isnan(y)) return 0.0f;
    if (isinf(y)) return y > 0.0f ? 1e4f : 1e-4f;
    return y;
}

// ================= CSR build =================
__global__ void k_hist(const int* __restrict__ idx, int* __restrict__ cnt, int n) {
    int e = blockIdx.x * blockDim.x + threadIdx.x;
    if (e < n) atomicAdd(&cnt[idx[e]], 1);
}

__global__ void k_scan1(const int* __restrict__ cnt, int* __restrict__ off,
                        int* __restrict__ bsum, int n) {
    __shared__ int sh[256];
    int t = threadIdx.x;
    int base = blockIdx.x * 1024 + t * 4;
    int v[4];
    #pragma unroll
    for (int j = 0; j < 4; j++) v[j] = (base + j < n) ? cnt[base + j] : 0;
    int tot = v[0] + v[1] + v[2] + v[3];
    sh[t] = tot;
    __syncthreads();
    for (int d = 1; d < 256; d <<= 1) {
        int x = (t >= d) ? sh[t - d] : 0;
        __syncthreads();
        sh[t] += x;
        __syncthreads();
    }
    int run = sh[t] - tot;
    #pragma unroll
    for (int j = 0; j < 4; j++) {
        if (base + j < n) off[base + j] = run;
        run += v[j];
    }
    if (t == 255) bsum[blockIdx.x] = sh[255];
}

__global__ void k_scan2(const int* __restrict__ bsum, int* __restrict__ bsx, int nb) {
    __shared__ int sh[256];
    int t = threadIdx.x;
    int v = (t < nb) ? bsum[t] : 0;
    sh[t] = v;
    __syncthreads();
    for (int d = 1; d < 256; d <<= 1) {
        int x = (t >= d) ? sh[t - d] : 0;
        __syncthreads();
        sh[t] += x;
        __syncthreads();
    }
    if (t < nb) bsx[t] = sh[t] - v;
    if (t == 255) bsx[nb] = sh[255];
}

__global__ void k_scan3(int* __restrict__ off, int* __restrict__ cur,
                        const int* __restrict__ bsx, int n, int nb) {
    int i = blockIdx.x * blockDim.x + threadIdx.x;
    if (i > n) return;
    int val = (i == n) ? bsx[nb] : off[i] + bsx[i >> 10];
    off[i] = val;
    if (i < n) cur[i] = val;
}

__global__ void k_scatterU(const int* __restrict__ ie, const float* __restrict__ w,
                           int* __restrict__ cur, int* __restrict__ csr_it,
                           float* __restrict__ csr_w, int n) {
    int e = blockIdx.x * blockDim.x + threadIdx.x;
    if (e >= n) return;
    int u = ie[e], it = ie[n + e];
    int pos = atomicAdd(&cur[u], 1);
    csr_it[pos] = it;
    csr_w[pos] = w[e];
}

__global__ void k_scatterT(const int* __restrict__ eidx, const int* __restrict__ etype,
                           int* __restrict__ cur, int* __restrict__ csr_tr, int n) {
    int e = blockIdx.x * blockDim.x + threadIdx.x;
    if (e >= n) return;
    int h = eidx[e], t = eidx[n + e], r = etype[e] - 1;
    int pos = atomicAdd(&cur[h], 1);
    csr_tr[pos] = t | (r << 20);
}

// ================= lane-owns-row tiled GEMM helpers =================
// Stage A-tile [64 rows x 64 k] transposed into LDS: At[k][row].
// src0 = rows' first 32 k (er / emb lo), src1 = next 32 (ei / emb hi) — for
// proj kernels the row is one 64-float array, handled by stride.
__device__ __forceinline__ void stage_rows2(const float* __restrict__ s0,
                                            const float* __restrict__ s1,
                                            float* At, int row0, int n, int t) {
    #pragma unroll
    for (int half = 0; half < 2; half++) {
        const float* src = half ? s1 : s0;
        int kofs = half ? 32 : 0;
        #pragma unroll
        for (int fi = t, it = 0; it < 2; fi += 256, it++) {
            int row = fi >> 3;
            int k4 = (fi & 7) << 2;
            float4 v = make_float4(0.f, 0.f, 0.f, 0.f);
            if (row0 + row < n) v = *(const float4*)&src[(size_t)(row0 + row) * 32 + k4];
            At[(kofs + k4 + 0) * 64 + row] = v.x;
            At[(kofs + k4 + 1) * 64 + row] = v.y;
            At[(kofs + k4 + 2) * 64 + row] = v.z;
            At[(kofs + k4 + 3) * 64 + row] = v.w;
        }
    }
}

// stage a [64 x 64] row-major source (stride 64 floats)
__device__ __forceinline__ void stage_rows1(const float* __restrict__ src,
                                            float* At, int row0, int n, int t) {
    #pragma unroll
    for (int fi = t, it = 0; it < 4; fi += 256, it++) {
        int row = fi >> 4;          // 16 float4 per row
        int k4 = (fi & 15) << 2;
        float4 v = make_float4(0.f, 0.f, 0.f, 0.f);
        if (row0 + row < n) v = *(const float4*)&src[(size_t)(row0 + row) * 64 + k4];
        At[(k4 + 0) * 64 + row] = v.x;
        At[(k4 + 1) * 64 + row] = v.y;
        At[(k4 + 2) * 64 + row] = v.z;
        At[(k4 + 3) * 64 + row] = v.w;
    }
}

// EH = [er|ei]@fpW1[0:64], ET = [er|ei]@fpW1[128:192]  (lane=row, 4 waves x 32 cols)
__global__ __launch_bounds__(256) void k_ent_ab(const float* __restrict__ er,
        const float* __restrict__ ei, const float* __restrict__ fpW1,
        float* __restrict__ EH, float* __restrict__ ET, int n) {
    __shared__ float At[64 * 64];
    int t = threadIdx.x;
    int row0 = blockIdx.x << 6;
    stage_rows2(er, ei, At, row0, n, t);
    __syncthreads();
    int lane = t & 63;
    int wv = __builtin_amdgcn_readfirstlane(t >> 6);
    const float* Wb = fpW1 + ((wv >> 1) ? (128 * 64) : 0) + (wv & 1) * 32;
    float acc[32];
    #pragma unroll
    for (int c = 0; c < 32; c++) acc[c] = 0.f;
    for (int k = 0; k < 64; k++) {
        float a = At[k * 64 + lane];
        const float* wr = Wb + k * 64;
        #pragma unroll
        for (int c4 = 0; c4 < 8; c4++) {
            float4 w4 = *(const float4*)&wr[c4 * 4];
            acc[c4 * 4 + 0] += a * w4.x;
            acc[c4 * 4 + 1] += a * w4.y;
            acc[c4 * 4 + 2] += a * w4.z;
            acc[c4 * 4 + 3] += a * w4.w;
        }
    }
    int row = row0 + lane;
    if (row < n) {
        float* dst = ((wv >> 1) ? ET : EH) + (size_t)row * 64 + (wv & 1) * 32;
        #pragma unroll
        for (int c4 = 0; c4 < 8; c4++)
            *(float4*)&dst[c4 * 4] = make_float4(acc[c4*4], acc[c4*4+1], acc[c4*4+2], acc[c4*4+3]);
    }
}

// PHI = [er|ei]@rtW1  (4 waves x 16 cols)
__global__ __launch_bounds__(256) void k_ent_phi(const float* __restrict__ er,
        const float* __restrict__ ei, const float* __restrict__ rtW1,
        float* __restrict__ PHI, int n) {
    __shared__ float At[64 * 64];
    int t = threadIdx.x;
    int row0 = blockIdx.x << 6;
    stage_rows2(er, ei, At, row0, n, t);
    __syncthreads();
    int lane = t & 63;
    int wv = __builtin_amdgcn_readfirstlane(t >> 6);
    const float* Wb = rtW1 + wv * 16;
    float acc[16];
    #pragma unroll
    for (int c = 0; c < 16; c++) acc[c] = 0.f;
    for (int k = 0; k < 64; k++) {
        float a = At[k * 64 + lane];
        const float* wr = Wb + k * 64;
        #pragma unroll
        for (int c4 = 0; c4 < 4; c4++) {
            float4 w4 = *(const float4*)&wr[c4 * 4];
            acc[c4 * 4 + 0] += a * w4.x;
            acc[c4 * 4 + 1] += a * w4.y;
            acc[c4 * 4 + 2] += a * w4.z;
            acc[c4 * 4 + 3] += a * w4.w;
        }
    }
    int row = row0 + lane;
    if (row < n) {
        float* dst = PHI + (size_t)row * 64 + wv * 16;
        #pragma unroll
        for (int c4 = 0; c4 < 4; c4++)
            *(float4*)&dst[c4 * 4] = make_float4(acc[c4*4], acc[c4*4+1], acc[c4*4+2], acc[c4*4+3]);
    }
}

// Uq = user_embed @ Wq  (4 waves x 16 cols)
__global__ __launch_bounds__(256) void k_proj_user(const float* __restrict__ U,
        const float* __restrict__ Wq, float* __restrict__ Uq, int n) {
    __shared__ float At[64 * 64];
    int t = threadIdx.x;
    int row0 = blockIdx.x << 6;
    stage_rows1(U, At, row0, n, t);
    __syncthreads();
    int lane = t & 63;
    int wv = __builtin_amdgcn_readfirstlane(t >> 6);
    const float* Wb = Wq + wv * 16;
    float acc[16];
    #pragma unroll
    for (int c = 0; c < 16; c++) acc[c] = 0.f;
    for (int k = 0; k < 64; k++) {
        float a = At[k * 64 + lane];
        const float* wr = Wb + k * 64;
        #pragma unroll
        for (int c4 = 0; c4 < 4; c4++) {
            float4 w4 = *(const float4*)&wr[c4 * 4];
            acc[c4 * 4 + 0] += a * w4.x;
            acc[c4 * 4 + 1] += a * w4.y;
            acc[c4 * 4 + 2] += a * w4.z;
            acc[c4 * 4 + 3] += a * w4.w;
        }
    }
    int row = row0 + lane;
    if (row < n) {
        float* dst = Uq + (size_t)row * 64 + wv * 16;
        #pragma unroll
        for (int c4 = 0; c4 < 4; c4++)
            *(float4*)&dst[c4 * 4] = make_float4(acc[c4*4], acc[c4*4+1], acc[c4*4+2], acc[c4*4+3]);
    }
}

// IkB (bf16) = item@Wk, Iv = item@Wv  (waves 0/1 -> Ik, 2/3 -> Iv; 32 cols each)
__global__ __launch_bounds__(256) void k_proj_item(const float* __restrict__ I,
        const float* __restrict__ Wk, const float* __restrict__ Wv,
        bf16* __restrict__ IkB, float* __restrict__ Iv, int n) {
    __shared__ float At[64 * 64];
    int t = threadIdx.x;
    int row0 = blockIdx.x << 6;
    stage_rows1(I, At, row0, n, t);
    __syncthreads();
    int lane = t & 63;
    int wv = __builtin_amdgcn_readfirstlane(t >> 6);
    const float* Wb = ((wv >> 1) ? Wv : Wk) + (wv & 1) * 32;
    float acc[32];
    #pragma unroll
    for (int c = 0; c < 32; c++) acc[c] = 0.f;
    for (int k = 0; k < 64; k++) {
        float a = At[k * 64 + lane];
        const float* wr = Wb + k * 64;
        #pragma unroll
        for (int c4 = 0; c4 < 8; c4++) {
            float4 w4 = *(const float4*)&wr[c4 * 4];
            acc[c4 * 4 + 0] += a * w4.x;
            acc[c4 * 4 + 1] += a * w4.y;
            acc[c4 * 4 + 2] += a * w4.z;
            acc[c4 * 4 + 3] += a * w4.w;
        }
    }
    int row = row0 + lane;
    if (row < n) {
        if (wv >> 1) {
            float* dst = Iv + (size_t)row * 64 + (wv & 1) * 32;
            #pragma unroll
            for (int c4 = 0; c4 < 8; c4++)
                *(float4*)&dst[c4 * 4] = make_float4(acc[c4*4], acc[c4*4+1], acc[c4*4+2], acc[c4*4+3]);
        } else {
            bf16* dst = IkB + (size_t)row * 64 + (wv & 1) * 32;
            #pragma unroll
            for (int c4 = 0; c4 < 8; c4++) {
                ushort4 s;
                s.x = f2bf_bits(acc[c4 * 4 + 0]);
                s.y = f2bf_bits(acc[c4 * 4 + 1]);
                s.z = f2bf_bits(acc[c4 * 4 + 2]);
                s.w = f2bf_bits(acc[c4 * 4 + 3]);
                *(ushort4*)&dst[c4 * 4] = s;
            }
        }
    }
}

// ================= Stage A edge kernels =================
__global__ void k_userA(const int* __restrict__ offU, const int* __restrict__ csr_it,
                        const float* __restrict__ csr_w, const float* __restrict__ Uq,
                        const bf16* __restrict__ IkB, float* __restrict__ exA,
                        float* __restrict__ denU, int n) {
    int u = (blockIdx.x * blockDim.x + threadIdx.x) >> 6;
    int lane = threadIdx.x & 63;
    if (u >= n) return;
    int s = offU[u], e = offU[u + 1];
    if (s == e) return;
    int l = lane & 15, g = lane >> 4;
    float4 qv = *(const float4*)&Uq[(size_t)u * D + l * 4];
    float den = 0.f;
    for (int j0 = s; j0 < e; j0 += 4) {
        int j = j0 + g;
        bool valid = j < e;
        int jj = valid ? j : s;
        int it = csr_it[jj];
        ushort4 ik = *(const ushort4*)&IkB[(size_t)it * D + l * 4];
        float d = qv.x * bits2f(ik.x) + qv.y * bits2f(ik.y) +
                  qv.z * bits2f(ik.z) + qv.w * bits2f(ik.w);
        float sc = g16_sum(d);
        float ex = valid ? expf(sc * 0.125f * csr_w[jj]) : 0.f;
        den += ex;
        if (valid && l == 0) exA[j] = ex;
    }
    den += __shfl_xor(den, 16, 64);
    den += __shfl_xor(den, 32, 64);
    if (lane == 0) denU[u] = den * (float)(e - s);  // den * deg
}

__global__ void k_userB(const int* __restrict__ offU, const int* __restrict__ csr_it,
                        const float* __restrict__ exA, const float* __restrict__ denU,
                        float* __restrict__ c, int n) {
    int u = (blockIdx.x * blockDim.x + threadIdx.x) >> 6;
    int lane = threadIdx.x & 63;
    if (u >= n) return;
    int s = offU[u], e = offU[u + 1];
    if (s == e) return;
    float inv = 1.0f / denU[u];
    for (int j = s + lane; j < e; j += 64)
        atomicAdd(&c[csr_it[j]], exA[j] * inv);
}

__global__ void k_pdense(const float* __restrict__ c, const float* __restrict__ Iv,
                         float* __restrict__ p, int n) {
    int lane = threadIdx.x & 63;
    int gw = blockIdx.x * 4 + (threadIdx.x >> 6);
    int nw = gridDim.x * 4;
    float acc = 0.f;
    for (int i = gw; i < n; i += nw) acc += c[i] * Iv[(size_t)i * D + lane];
    __shared__ float red[256];
    red[threadIdx.x] = acc;
    __syncthreads();
    if (threadIdx.x < 64) {
        float s = red[threadIdx.x] + red[threadIdx.x + 64] + red[threadIdx.x + 128] + red[threadIdx.x + 192];
        atomicAdd(&p[threadIdx.x], s);
    }
}

__global__ void k_v2(const float* __restrict__ rtW2, const float* __restrict__ rt_b2,
                     const float* __restrict__ p, float* __restrict__ v2, float* __restrict__ cb) {
    int j = threadIdx.x;  // 64 threads
    float acc = 0.f;
    #pragma unroll
    for (int k = 0; k < D; k++) acc += rtW2[j * D + k] * p[k];
    v2[j] = acc;
    float c = rt_b2[j] * p[j];
    c = wave_sum(c);
    if (j == 0) cb[0] = c;
}

// ================= Stage B =================
__global__ void k_rel_tables(const float* __restrict__ rr, const float* __restrict__ ri,
                             const float* __restrict__ fpW1, const float* __restrict__ rtW1,
                             float* __restrict__ RR1, float* __restrict__ PSI) {
    int lane = threadIdx.x;  // 64
    for (int r = 0; r < 10; r++) {
        float a = 0.f, b = 0.f;
        for (int k = 0; k < 32; k++) {
            float sr = rr[r * 32 + k], si = ri[r * 32 + k];
            a += sr * fpW1[(64 + k) * D + lane] + si * fpW1[(96 + k) * D + lane];
            b += sr * rtW1[k * D + lane] + si * rtW1[(32 + k) * D + lane];
        }
        RR1[r * D + lane] = a;
        PSI[r * D + lane] = b;
    }
}

// wave/head, 16-lane subgroups, 4 edges in flight: gate weights
__global__ void k_omega1(const int* __restrict__ offH, const int* __restrict__ csr_tr,
                         const float* __restrict__ EH, const float* __restrict__ ET,
                         const float* __restrict__ RR1, const float* __restrict__ fp_b1,
                         const float* __restrict__ fpW2, const float* __restrict__ fp_b2,
                         float* __restrict__ w0a, float* __restrict__ w1a,
                         float* __restrict__ w2a, int n) {
    int h = (blockIdx.x * blockDim.x + threadIdx.x) >> 6;
    int lane = threadIdx.x & 63;
    if (h >= n) return;
    int s = offH[h], e = offH[h + 1];
    if (s == e) return;
    int l = lane & 15, g = lane >> 4;
    int d0 = l * 4;
    float4 ehh = *(const float4*)&EH[(size_t)h * D + d0];
    float4 b1 = *(const float4*)&fp_b1[d0];
    ehh.x += b1.x; ehh.y += b1.y; ehh.z += b1.z; ehh.w += b1.w;
    float f0[4], f1[4], f2[4];
    #pragma unroll
    for (int cc = 0; cc < 4; cc++) {
        f0[cc] = fpW2[(d0 + cc) * 3 + 0];
        f1[cc] = fpW2[(d0 + cc) * 3 + 1];
        f2[cc] = fpW2[(d0 + cc) * 3 + 2];
    }
    float b20 = fp_b2[0], b21 = fp_b2[1], b22 = fp_b2[2];
    for (int j0 = s; j0 < e; j0 += 4) {
        int j = j0 + g;
        bool valid = j < e;
        int jj = valid ? j : s;
        int pk = csr_tr[jj];
        int t = pk & 0xFFFFF, r = pk >> 20;
        float4 et = *(const float4*)&ET[(size_t)t * D + d0];
        float4 rr = *(const float4*)&RR1[r * D + d0];
        float z0 = sigmoidf(ehh.x + rr.x + et.x);
        float z1 = sigmoidf(ehh.y + rr.y + et.y);
        float z2 = sigmoidf(ehh.z + rr.z + et.z);
        float z3 = sigmoidf(ehh.w + rr.w + et.w);
        float a0 = z0 * f0[0] + z1 * f0[1] + z2 * f0[2] + z3 * f0[3];
        float a1 = z0 * f1[0] + z1 * f1[1] + z2 * f1[2] + z3 * f1[3];
        float a2 = z0 * f2[0] + z1 * f2[1] + z2 * f2[2] + z3 * f2[3];
        a0 = g16_sum(a0); a1 = g16_sum(a1); a2 = g16_sum(a2);
        if (valid && l == 0) {
            a0 += b20; a1 += b21; a2 += b22;
            float mx = fmaxf(a0, fmaxf(a1, a2));
            float e0 = expf(a0 - mx), e1 = expf(a1 - mx), e2 = expf(a2 - mx);
            float inv = 1.0f / (e0 + e1 + e2);
            w0a[j] = e0 * inv;
            w1a[j] = e1 * inv;
            w2a[j] = e2 * inv;
        }
    }
}

// wave/head, subgroups: omega + local seg_o
__global__ void k_omega2a(const int* __restrict__ offH, const int* __restrict__ csr_tr,
                          const float* __restrict__ PHI, const float* __restrict__ PSI,
                          const float* __restrict__ rt_b1, const float* __restrict__ v2,
                          const float* __restrict__ cb, const float* __restrict__ w0a,
                          const float* __restrict__ w1a, const float* __restrict__ w2a,
                          float* __restrict__ omg, float* __restrict__ segO, int n) {
    int h = (blockIdx.x * blockDim.x + threadIdx.x) >> 6;
    int lane = threadIdx.x & 63;
    if (h >= n) return;
    int s = offH[h], e = offH[h + 1];
    if (s == e) return;
    int l = lane & 15, g = lane >> 4;
    int d0 = l * 4;
    float4 phh = *(const float4*)&PHI[(size_t)h * D + d0];
    float4 rb = *(const float4*)&rt_b1[d0];
    float4 vv = *(const float4*)&v2[d0];
    float cc = cb[0];
    float so = 0.f;
    for (int j0 = s; j0 < e; j0 += 4) {
        int j = j0 + g;
        bool valid = j < e;
        int jj = valid ? j : s;
        int pk = csr_tr[jj];
        int t = pk & 0xFFFFF, r = pk >> 20;
        float W0 = w0a[jj], W1 = w1a[jj], W2 = w2a[jj];
        float4 pt = *(const float4*)&PHI[(size_t)t * D + d0];
        float4 ps = *(const float4*)&PSI[r * D + d0];
        float sv = sigmoidf(W0 * phh.x + W1 * ps.x + W2 * pt.x + rb.x) * vv.x
                 + sigmoidf(W0 * phh.y + W1 * ps.y + W2 * pt.y + rb.y) * vv.y
                 + sigmoidf(W0 * phh.z + W1 * ps.z + W2 * pt.z + rb.z) * vv.z
                 + sigmoidf(W0 * phh.w + W1 * ps.w + W2 * pt.w + rb.w) * vv.w;
        sv = g16_sum(sv);
        float om = (sv + cc) * 0.125f;
        if (valid) {
            if (l == 0) omg[j] = om;
            so += om;
        }
    }
    so += __shfl_xor(so, 16, 64);
    so += __shfl_xor(so, 32, 64);
    if (lane == 0) segO[h] = so;
}

__global__ void k_omega2b(const int* __restrict__ offH, const float* __restrict__ omg,
                          const float* __restrict__ segO, float* __restrict__ csr_a,
                          float* __restrict__ csr_et, int n) {
    int h = (blockIdx.x * blockDim.x + threadIdx.x) >> 6;
    int lane = threadIdx.x & 63;
    if (h >= n) return;
    int s = offH[h], e = offH[h + 1];
    if (s == e) return;
    float invO = 1.0f / (segO[h] + 1e-8f);
    float se = 0.f;
    for (int j = s + lane; j < e; j += 64) {
        float a = omg[j] * invO;
        csr_a[j] = a;
        se += (a > GAMMA) ? a : 0.0f;
    }
    se = wave_sum(se);
    float invE = 1.0f / (se + 1e-8f);
    for (int j = s + lane; j < e; j += 64) {
        float a = csr_a[j];
        csr_et[j] = ((a > GAMMA) ? a : 0.0f) * invE;
    }
}

// ================= hops =================
__global__ void k_cvt(const float* __restrict__ src, bf16* __restrict__ dst, int n) {
    int i = blockIdx.x * blockDim.x + threadIdx.x;
    if (i < n) dst[i] = __float2bfloat16(src[i]);
}

__global__ void k_hop_e(const int* __restrict__ off, const int* __restrict__ tr,
                        const float* __restrict__ rho, const float* __restrict__ rel,
                        const bf16* __restrict__ ecur, bf16* __restrict__ enxt,
                        const float* __restrict__ initE, float* __restrict__ out,
                        int init, int n) {
    int gw = (blockIdx.x * blockDim.x + threadIdx.x) >> 6;
    int lane = threadIdx.x & 63;
    if (gw >= n) return;
    int s = off[gw], e = off[gw + 1];
    int l = lane & 15, g = lane >> 4;
    int d0 = l * 4;
    float a0 = 0.f, a1 = 0.f, a2 = 0.f, a3 = 0.f;
    for (int j0 = s; j0 < e; j0 += 4) {
        int j = j0 + g;
        bool valid = j < e;
        int jj = valid ? j : s;
        int pk = tr[jj];
        int t = pk & 0xFFFFF, r = pk >> 20;
        float rh = valid ? rho[jj] : 0.f;
        ushort4 ev = *(const ushort4*)&ecur[(size_t)t * D + d0];
        float4 rl = *(const float4*)&rel[r * D + d0];
        a0 += rh * bits2f(ev.x) * rl.x;
        a1 += rh * bits2f(ev.y) * rl.y;
        a2 += rh * bits2f(ev.z) * rl.z;
        a3 += rh * bits2f(ev.w) * rl.w;
    }
    a0 += __shfl_xor(a0, 16, 64); a0 += __shfl_xor(a0, 32, 64);
    a1 += __shfl_xor(a1, 16, 64); a1 += __shfl_xor(a1, 32, 64);
    a2 += __shfl_xor(a2, 16, 64); a2 += __shfl_xor(a2, 32, 64);
    a3 += __shfl_xor(a3, 16, 64); a3 += __shfl_xor(a3, 32, 64);
    float invd = 1.0f / fmaxf((float)(e - s), 1.0f);
    a0 *= invd; a1 *= invd; a2 *= invd; a3 *= invd;
    float ss = a0 * a0 + a1 * a1 + a2 * a2 + a3 * a3;
    ss = g16_sum(ss);
    float nrm = fmaxf(sqrtf(ss), 1e-8f);
    float y0 = n2n(a0 / nrm), y1 = n2n(a1 / nrm), y2 = n2n(a2 / nrm), y3 = n2n(a3 / nrm);
    if (g == 0) {
        ushort4 st;
        st.x = f2bf_bits(y0); st.y = f2bf_bits(y1); st.z = f2bf_bits(y2); st.w = f2bf_bits(y3);
        *(ushort4*)&enxt[(size_t)gw * D + d0] = st;
        size_t o = (size_t)gw * D + d0;
        float4 prev;
        if (init) prev = *(const float4*)&initE[o];
        else      prev = *(const float4*)&out[o];
        *(float4*)&out[o] = make_float4(prev.x + y0, prev.y + y1, prev.z + y2, prev.w + y3);
    }
}

__global__ void k_hop_u(const int* __restrict__ off, const int* __restrict__ itArr,
                        const float* __restrict__ wArr, const bf16* __restrict__ ecur,
                        const float* __restrict__ initU, float* __restrict__ out,
                        int init, int n) {
    int gw = (blockIdx.x * blockDim.x + threadIdx.x) >> 6;
    int lane = threadIdx.x & 63;
    if (gw >= n) return;
    int s = off[gw], e = off[gw + 1];
    int l = lane & 15, g = lane >> 4;
    int d0 = l * 4;
    float a0 = 0.f, a1 = 0.f, a2 = 0.f, a3 = 0.f;
    for (int j0 = s; j0 < e; j0 += 4) {
        int j = j0 + g;
        bool valid = j < e;
        int jj = valid ? j : s;
        int it = itArr[jj];
        float w = valid ? wArr[jj] : 0.f;
        ushort4 ev = *(const ushort4*)&ecur[(size_t)it * D + d0];
        a0 += w * bits2f(ev.x);
        a1 += w * bits2f(ev.y);
        a2 += w * bits2f(ev.z);
        a3 += w * bits2f(ev.w);
    }
    a0 += __shfl_xor(a0, 16, 64); a0 += __shfl_xor(a0, 32, 64);
    a1 += __shfl_xor(a1, 16, 64); a1 += __shfl_xor(a1, 32, 64);
    a2 += __shfl_xor(a2, 16, 64); a2 += __shfl_xor(a2, 32, 64);
    a3 += __shfl_xor(a3, 16, 64); a3 += __shfl_xor(a3, 32, 64);
    float ss = a0 * a0 + a1 * a1 + a2 * a2 + a3 * a3;
    ss = g16_sum(ss);
    float nrm = fmaxf(sqrtf(ss), 1e-8f);
    float y0 = n2n(a0 / nrm), y1 = n2n(a1 / nrm), y2 = n2n(a2 / nrm), y3 = n2n(a3 / nrm);
    if (g == 0) {
        size_t o = (size_t)gw * D + d0;
        float4 prev;
        if (init) prev = *(const float4*)&initU[o];
        else      prev = *(const float4*)&out[o];
        *(float4*)&out[o] = make_float4(prev.x + y0, prev.y + y1, prev.z + y2, prev.w + y3);
    }
}

extern "C" void kernel_launch(void* const* d_in, const int* in_sizes, int n_in,
                              void* d_out, int out_size, void* d_ws, size_t ws_size,
                              hipStream_t stream) {
    const float* user_embed = (const float*)d_in[0];
    const float* item_embed = (const float*)d_in[1];
    const float* Wq = (const float*)d_in[2];
    const float* Wk = (const float*)d_in[3];
    const float* Wv = (const float*)d_in[4];
    const float* ent_real = (const float*)d_in[5];
    const float* ent_imag = (const float*)d_in[6];
    const float* rel_real = (const float*)d_in[7];
    const float* rel_imag = (const float*)d_in[8];
    const float* fp_W1 = (const float*)d_in[9];
    const float* fp_b1 = (const float*)d_in[10];
    const float* fp_W2 = (const float*)d_in[11];
    const float* fp_b2 = (const float*)d_in[12];
    const float* rt_W1 = (const float*)d_in[13];
    const float* rt_b1 = (const float*)d_in[14];
    const float* rt_W2 = (const float*)d_in[15];
    const float* rt_b2 = (const float*)d_in[16];
    const float* relation_emb = (const float*)d_in[17];
    const float* user_emb = (const float*)d_in[18];
    const float* entity_emb = (const float*)d_in[19];
    const float* inter_edge_w = (const float*)d_in[20];
    const int* edge_index = (const int*)d_in[21];
    const int* edge_type = (const int*)d_in[22];
    const int* inter_edge = (const int*)d_in[23];
    float* out = (float*)d_out;

    float* W = (float*)d_ws;
    size_t off = 0;
    auto alloc = [&](size_t n) { float* r = W + off; off += n; return r; };
    // persistent floats
    float* omg    = alloc(NE);
    float* w0a    = alloc(NE);
    float* w1a    = alloc(NE);
    float* w2a    = alloc(NE);
    float* segO   = alloc(N_ENT);
    float* denU   = alloc(N_USERS);
    float* c      = alloc(N_ITEMS);
    float* exA    = alloc(NEI);
    float* csr_a  = alloc(NE);
    float* csr_et = alloc(NE);
    float* csr_w  = alloc(NEI);
    float* p      = alloc(64);
    float* v2     = alloc(64);
    float* cb     = alloc(64);
    float* RR1    = alloc(10 * D);
    float* PSI    = alloc(10 * D);
    // persistent ints
    int* IW = (int*)(W + off);
    size_t ioff = 0;
    auto ialloc = [&](size_t n) { int* r = IW + ioff; ioff += n; return r; };
    int* cntU   = ialloc(N_USERS);
    int* offU   = ialloc(N_USERS + 1);
    int* curU   = ialloc(N_USERS);
    int* cntH   = ialloc(N_ENT);
    int* offH   = ialloc(N_ENT + 1);
    int* curH   = ialloc(N_ENT);
    int* bsumU  = ialloc(256);
    int* bsxU   = ialloc(257);
    int* bsumH  = ialloc(256);
    int* bsxH   = ialloc(257);
    int* csr_tr = ialloc(NE);
    int* csr_it = ialloc(NEI);
    off += ioff;
    // union region
    float* U = W + off;
    // phase A
    bf16*  IkB = (bf16*)U;
    float* Iv  = U + (size_t)N_ITEMS * 32;
    float* Uq  = Iv + (size_t)N_ITEMS * D;
    // phase B
    float* EH  = U;
    float* ET  = EH + (size_t)N_ENT * D;
    float* PHI = U;                          // overwrites EH after k_omega1
    // phase C
    bf16* eA = (bf16*)U;
    bf16* eB = (bf16*)(U + (size_t)N_ENT * 32);

    const int nbU = (N_USERS + 1023) / 1024;
    const int nbH = (N_ENT + 1023) / 1024;

    // ---- CSR build ----
    hipMemsetAsync(cntU, 0, N_USERS * 4, stream);
    hipMemsetAsync(cntH, 0, N_ENT * 4, stream);
    k_hist<<<(NEI + 255) / 256, 256, 0, stream>>>(inter_edge, cntU, NEI);
    k_hist<<<(NE + 255) / 256, 256, 0, stream>>>(edge_index, cntH, NE);
    k_scan1<<<nbU, 256, 0, stream>>>(cntU, offU, bsumU, N_USERS);
    k_scan2<<<1, 256, 0, stream>>>(bsumU, bsxU, nbU);
    k_scan3<<<(N_USERS + 256) / 256, 256, 0, stream>>>(offU, curU, bsxU, N_USERS, nbU);
    k_scan1<<<nbH, 256, 0, stream>>>(cntH, offH, bsumH, N_ENT);
    k_scan2<<<1, 256, 0, stream>>>(bsumH, bsxH, nbH);
    k_scan3<<<(N_ENT + 256) / 256, 256, 0, stream>>>(offH, curH, bsxH, N_ENT, nbH);
    k_scatterU<<<(NEI + 255) / 256, 256, 0, stream>>>(inter_edge, inter_edge_w, curU,
                                                      csr_it, csr_w, NEI);
    k_scatterT<<<(NE + 255) / 256, 256, 0, stream>>>(edge_index, edge_type, curH, csr_tr, NE);

    // ---- Phase A ----
    hipMemsetAsync(c, 0, N_ITEMS * 4, stream);
    hipMemsetAsync(p, 0, 64 * 4, stream);
    k_proj_item<<<(N_ITEMS + 63) / 64, 256, 0, stream>>>(item_embed, Wk, Wv, IkB, Iv, N_ITEMS);
    k_proj_user<<<(N_USERS + 63) / 64, 256, 0, stream>>>(user_embed, Wq, Uq, N_USERS);
    k_userA<<<(N_USERS + 3) / 4, 256, 0, stream>>>(offU, csr_it, csr_w, Uq, IkB,
                                                   exA, denU, N_USERS);
    k_userB<<<(N_USERS + 3) / 4, 256, 0, stream>>>(offU, csr_it, exA, denU, c, N_USERS);
    k_pdense<<<64, 256, 0, stream>>>(c, Iv, p, N_ITEMS);
    k_v2<<<1, 64, 0, stream>>>(rt_W2, rt_b2, p, v2, cb);

    // ---- Phase B ----
    k_ent_ab<<<(N_ENT + 63) / 64, 256, 0, stream>>>(ent_real, ent_imag, fp_W1, EH, ET, N_ENT);
    k_rel_tables<<<1, 64, 0, stream>>>(rel_real, rel_imag, fp_W1, rt_W1, RR1, PSI);
    k_omega1<<<(N_ENT + 3) / 4, 256, 0, stream>>>(offH, csr_tr, EH, ET, RR1, fp_b1,
                                                  fp_W2, fp_b2, w0a, w1a, w2a, N_ENT);
    k_ent_phi<<<(N_ENT + 63) / 64, 256, 0, stream>>>(ent_real, ent_imag, rt_W1, PHI, N_ENT);
    k_omega2a<<<(N_ENT + 3) / 4, 256, 0, stream>>>(offH, csr_tr, PHI, PSI, rt_b1, v2, cb,
                                                   w0a, w1a, w2a, omg, segO, N_ENT);
    k_omega2b<<<(N_ENT + 3) / 4, 256, 0, stream>>>(offH, omg, segO, csr_a, csr_et, N_ENT);

    // ---- hops ----
    k_cvt<<<(N_ENT * D + 255) / 256, 256, 0, stream>>>(entity_emb, eA, N_ENT * D);
    bf16* ecur = eA;
    bf16* enxt = eB;
    for (int hop = 1; hop <= 3; hop++) {
        const float* rho = (hop < 3) ? csr_a : csr_et;
        int init = (hop == 1) ? 1 : 0;
        k_hop_e<<<(N_ENT + 3) / 4, 256, 0, stream>>>(offH, csr_tr, rho, relation_emb,
                                                     ecur, enxt, entity_emb, out, init, N_ENT);
        k_hop_u<<<(N_USERS + 3) / 4, 256, 0, stream>>>(offU, csr_it, csr_w, ecur,
                                                       user_emb, out + (size_t)N_ENT * D,
                                                       init, N_USERS);
        bf16* tmp = ecur; ecur = enxt; enxt = tmp;
    }
}